// Round 8
// baseline (1102.328 us; speedup 1.0000x reference)
//
#include <hip/hip_runtime.h>

#define N_USERS 100000
#define N_ITEMS 50000
#define N_NODES 150000
#define N_REL 5
#define NNZ 2000000
#define D 64
#define B_EVAL 16384
#define MAXSLOTS 32768
#define NBUCKET 4096                  /* bucket = ci>>3 : 8 slots x 5 rels = 40 bins */
#define NSTRIPE 8
#define NSB (NBUCKET * NSTRIPE)       /* 32768 stripe-bucket segments */
#define TOTAL_EDGES (N_REL * NNZ)     /* 10,000,000 */
#define RECCAP 2000000                /* passing edges ~1.94M (deterministic input) */

// -------- workspace layout (bytes) ----
// map:    int[150000]        @ 0
// cnt:    int                @ 600,064
// cntsb:  int[32768]         @ 600,320     (131 KB)
// offs:   int[32768]         @ 731,392     (131 KB)
// recs:   uint2[2,000,000]   @ 862,464     (16.0 MB)
// agg:    bf16[32768*320]    @ 16,862,464  (21.0 MB)
// logits: float[32768*64]    @ 862,464     (overlaps recs - dead after gather)
// total footprint: 37,833,984 B
#define OFF_MAP   0
#define OFF_CNT   600064
#define OFF_CSB   600320
#define OFF_OFFS  731392
#define OFF_RECS  862464
#define OFF_AGG   16862464
#define OFF_LOG   862464

__device__ __forceinline__ unsigned short f2bf(float f) {   // RNE f32->bf16
    unsigned u = __float_as_uint(f);
    return (unsigned short)((u + 0x7FFFu + ((u >> 16) & 1u)) >> 16);
}
__device__ __forceinline__ float bflo(unsigned p) { return __uint_as_float(p << 16); }
__device__ __forceinline__ float bfhi(unsigned p) { return __uint_as_float(p & 0xFFFF0000u); }

__global__ __launch_bounds__(256) void build_map(const int* __restrict__ users,
                                                 const int* __restrict__ items,
                                                 int* __restrict__ map,
                                                 int* __restrict__ cnt) {
    int t = blockIdx.x * 256 + threadIdx.x;
    if (t >= 2 * B_EVAL) return;
    int node = (t < B_EVAL) ? users[t] : (N_USERS + items[t - B_EVAL]);
    if (atomicCAS(&map[node], -1, -2) == -1) {
        int idx = atomicAdd(cnt, 1);
        map[node] = idx;
    }
}

// Count per (stripe, bucket): stripe = blockIdx&7 matches fill_records exactly
// (same grid/block mapping), so counts == fills per segment deterministically.
__global__ __launch_bounds__(256) void count_sb(const int* __restrict__ rows,
                                                const int* __restrict__ map,
                                                int* __restrict__ cntsb) {
    int gid = blockIdx.x * 256 + threadIdx.x;
    if (gid >= TOTAL_EDGES) return;
    int ci = map[rows[gid]];
    if (ci >= 0)
        atomicAdd(&cntsb[(blockIdx.x & 7) * NBUCKET + (ci >> 3)], 1);
}

// Exclusive scan of 32768 counts: one block, 32 elems/thread serial + Hillis-Steele.
__global__ __launch_bounds__(1024) void scan_sb(const int* __restrict__ cntsb,
                                                int* __restrict__ offs) {
    __shared__ int sh[1024];
    int t = threadIdx.x;
    int base = t * 32;
    int sum = 0;
    #pragma unroll
    for (int i = 0; i < 32; i++) sum += cntsb[base + i];
    sh[t] = sum;
    __syncthreads();
    int acc = sum;
    for (int off = 1; off < 1024; off <<= 1) {
        int add = (t >= off) ? sh[t - off] : 0;
        __syncthreads();
        acc += add;
        sh[t] = acc;
        __syncthreads();
    }
    int run = acc - sum;                 // exclusive prefix of this thread's chunk
    #pragma unroll
    for (int i = 0; i < 32; i++) {
        int v = cntsb[base + i];
        offs[base + i] = run;
        run += v;
    }
}

// Scatter records into 32K append segments. Active-line working set = 32K cursors
// (256 KB) + 1 open record line per segment -> lines fill fast and write-combine.
// Record packs binLocal (6b: (ci&7)*5+rel) above the 18-bit col index.
__global__ __launch_bounds__(256) void fill_records(const int* __restrict__ rows,
                                                    const int* __restrict__ cols,
                                                    const float* __restrict__ vals,
                                                    const int* __restrict__ map,
                                                    int* __restrict__ offs,
                                                    uint2* __restrict__ recs) {
    int gid = blockIdx.x * 256 + threadIdx.x;
    if (gid >= TOTAL_EDGES) return;
    int ci = map[rows[gid]];
    if (ci < 0) return;
    int rel = gid / NNZ;
    int sb = (blockIdx.x & 7) * NBUCKET + (ci >> 3);
    int pos = atomicAdd(&offs[sb], 1);
    unsigned bl = (unsigned)((ci & 7) * N_REL + rel);
    if (pos < RECCAP)
        recs[pos] = make_uint2((unsigned)cols[gid] | (bl << 18), __float_as_uint(vals[gid]));
}

// One block per bucket: 2 waves, LDS fp32 accumulator [40 bins][64 dims] = 10 KB.
// Wave w walks stripes 4w..4w+3 via select-chain; ds_add_f32 atomics resolve
// all same-bin races (inter-wave and unroll-4). Output: coalesced bf16 store.
__global__ __launch_bounds__(128) void gather_buckets(const uint2* __restrict__ recs,
                                                      const float* __restrict__ uemb,
                                                      const float* __restrict__ iemb,
                                                      const int* __restrict__ offs,
                                                      const int* __restrict__ cntsb,
                                                      const int* __restrict__ cnt,
                                                      unsigned short* __restrict__ agg) {
    __shared__ float lds[40 * 64];
    int b = blockIdx.x;
    int tid = threadIdx.x;
    int lane = tid & 63;
    int w = tid >> 6;
    int cval = *cnt;
    if (b * 8 >= cval) return;

    for (int i = tid; i < 40 * 64; i += 128) lds[i] = 0.0f;
    __syncthreads();

    int bs[4], ce[4];
    #pragma unroll
    for (int s = 0; s < 4; s++) {
        int sg = (w * 4 + s) * NBUCKET + b;
        int c = cntsb[sg];
        bs[s] = offs[sg] - c;            // post-fill: offs = segment end
        ce[s] = (s == 0 ? 0 : ce[s - 1]) + c;
    }
    int T = ce[3];

    auto A = [&](int idx) {              // flat index -> record address
        int a = bs[0] + idx;
        #pragma unroll
        for (int s = 1; s < 4; s++) {
            int r = idx - ce[s - 1];
            a = (r >= 0) ? (bs[s] + r) : a;
        }
        return a;
    };

    int i = 0;
    for (; i + 4 <= T; i += 4) {
        int a0 = A(i), a1 = A(i + 1), a2 = A(i + 2), a3 = A(i + 3);
        uint2 r0 = recs[a0], r1 = recs[a1], r2 = recs[a2], r3 = recs[a3];
        unsigned c0 = r0.x & 0x3FFFFu, c1 = r1.x & 0x3FFFFu;
        unsigned c2 = r2.x & 0x3FFFFu, c3 = r3.x & 0x3FFFFu;
        const float* p0 = (c0 < N_USERS) ? uemb + (size_t)c0 * D : iemb + (size_t)(c0 - N_USERS) * D;
        const float* p1 = (c1 < N_USERS) ? uemb + (size_t)c1 * D : iemb + (size_t)(c1 - N_USERS) * D;
        const float* p2 = (c2 < N_USERS) ? uemb + (size_t)c2 * D : iemb + (size_t)(c2 - N_USERS) * D;
        const float* p3 = (c3 < N_USERS) ? uemb + (size_t)c3 * D : iemb + (size_t)(c3 - N_USERS) * D;
        float e0 = p0[lane], e1 = p1[lane], e2 = p2[lane], e3 = p3[lane];
        atomicAdd(&lds[(r0.x >> 18) * 64 + lane], __uint_as_float(r0.y) * e0);
        atomicAdd(&lds[(r1.x >> 18) * 64 + lane], __uint_as_float(r1.y) * e1);
        atomicAdd(&lds[(r2.x >> 18) * 64 + lane], __uint_as_float(r2.y) * e2);
        atomicAdd(&lds[(r3.x >> 18) * 64 + lane], __uint_as_float(r3.y) * e3);
    }
    for (; i < T; i++) {
        int a = A(i);
        uint2 r = recs[a];
        unsigned c = r.x & 0x3FFFFu;
        const float* p = (c < N_USERS) ? uemb + (size_t)c * D : iemb + (size_t)(c - N_USERS) * D;
        atomicAdd(&lds[(r.x >> 18) * 64 + lane], __uint_as_float(r.y) * p[lane]);
    }
    __syncthreads();

    // lds[binLocal*64+d] maps linearly to agg[b*2560 + binLocal*64 + d]
    unsigned* out = (unsigned*)(agg + (size_t)b * 2560);
    for (int k = tid; k < 1280; k += 128) {
        float f0 = lds[2 * k], f1 = lds[2 * k + 1];
        out[k] = (unsigned)f2bf(f0) | ((unsigned)f2bf(f1) << 16);
    }
}

// LDS-tiled fused dense: 32 slots/block, 256 threads, 2x4 register tile/thread.
__global__ __launch_bounds__(256) void dense_tile(const unsigned short* __restrict__ agg,
                                                  const float* __restrict__ Wrel,
                                                  const float* __restrict__ brel,
                                                  const float* __restrict__ affW,
                                                  const float* __restrict__ affb,
                                                  const int* __restrict__ cnt,
                                                  float* __restrict__ logits) {
    __shared__ __align__(16) unsigned short shA[32][328];
    __shared__ __align__(16) unsigned short shM1[32][328];
    __shared__ __align__(16) float shW[64][68];

    int tid = threadIdx.x;
    int ty = tid >> 4, tx = tid & 15;
    int s0 = ty * 2;
    int j0 = tx * 4;
    int cval = *cnt;

    for (int tile = blockIdx.x; tile * 32 < cval; tile += gridDim.x) {
        __syncthreads();
        {
            const uint4* src = (const uint4*)(agg + (size_t)tile * 32 * 320);
            #pragma unroll
            for (int i = 0; i < 5; i++) {
                int idx = tid + i * 256;
                int p = idx * 8;
                int row = p / 320, col = p % 320;
                *(uint4*)&shA[row][col] = src[idx];
            }
        }
        #pragma unroll
        for (int k = 0; k < N_REL; k++) {
            __syncthreads();
            const float4* wsrc = (const float4*)(Wrel + (size_t)k * 4096);
            #pragma unroll
            for (int i = 0; i < 4; i++) {
                int idx = tid + i * 256;
                *(float4*)&shW[idx >> 4][(idx & 15) * 4] = wsrc[idx];
            }
            __syncthreads();
            float acc[2][4];
            #pragma unroll
            for (int jj = 0; jj < 4; jj++) {
                float b = brel[k * 64 + j0 + jj];
                acc[0][jj] = b; acc[1][jj] = b;
            }
            for (int d = 0; d < 64; d += 2) {
                unsigned pa0 = *(const unsigned*)&shA[s0][k * 64 + d];
                unsigned pa1 = *(const unsigned*)&shA[s0 + 1][k * 64 + d];
                float4 w0 = *(const float4*)&shW[d][j0];
                float4 w1 = *(const float4*)&shW[d + 1][j0];
                float a00 = bflo(pa0), a01 = bfhi(pa0);
                float a10 = bflo(pa1), a11 = bfhi(pa1);
                acc[0][0] = fmaf(a00, w0.x, fmaf(a01, w1.x, acc[0][0]));
                acc[0][1] = fmaf(a00, w0.y, fmaf(a01, w1.y, acc[0][1]));
                acc[0][2] = fmaf(a00, w0.z, fmaf(a01, w1.z, acc[0][2]));
                acc[0][3] = fmaf(a00, w0.w, fmaf(a01, w1.w, acc[0][3]));
                acc[1][0] = fmaf(a10, w0.x, fmaf(a11, w1.x, acc[1][0]));
                acc[1][1] = fmaf(a10, w0.y, fmaf(a11, w1.y, acc[1][1]));
                acc[1][2] = fmaf(a10, w0.z, fmaf(a11, w1.z, acc[1][2]));
                acc[1][3] = fmaf(a10, w0.w, fmaf(a11, w1.w, acc[1][3]));
            }
            #pragma unroll
            for (int i = 0; i < 2; i++) {
                #pragma unroll
                for (int jj = 0; jj < 4; jj++) {
                    float v = acc[i][jj];
                    acc[i][jj] = (v > 0.0f) ? v : 0.2f * v;   // leaky_relu 0.2
                }
                unsigned lo = (unsigned)f2bf(acc[i][0]) | ((unsigned)f2bf(acc[i][1]) << 16);
                unsigned hi = (unsigned)f2bf(acc[i][2]) | ((unsigned)f2bf(acc[i][3]) << 16);
                *(uint2*)&shM1[s0 + i][k * 64 + j0] = make_uint2(lo, hi);
            }
        }
        float acc2[2][4] = {{0,0,0,0},{0,0,0,0}};
        #pragma unroll
        for (int c = 0; c < N_REL; c++) {
            __syncthreads();
            const float4* wsrc = (const float4*)(affW + (size_t)c * 4096);
            #pragma unroll
            for (int i = 0; i < 4; i++) {
                int idx = tid + i * 256;
                *(float4*)&shW[idx >> 4][(idx & 15) * 4] = wsrc[idx];
            }
            __syncthreads();
            for (int dd = 0; dd < 64; dd += 2) {
                unsigned m0 = *(const unsigned*)&shM1[s0][c * 64 + dd];
                unsigned m1 = *(const unsigned*)&shM1[s0 + 1][c * 64 + dd];
                float4 w0 = *(const float4*)&shW[dd][j0];
                float4 w1 = *(const float4*)&shW[dd + 1][j0];
                float a00 = bflo(m0), a01 = bfhi(m0);
                float a10 = bflo(m1), a11 = bfhi(m1);
                acc2[0][0] = fmaf(a00, w0.x, fmaf(a01, w1.x, acc2[0][0]));
                acc2[0][1] = fmaf(a00, w0.y, fmaf(a01, w1.y, acc2[0][1]));
                acc2[0][2] = fmaf(a00, w0.z, fmaf(a01, w1.z, acc2[0][2]));
                acc2[0][3] = fmaf(a00, w0.w, fmaf(a01, w1.w, acc2[0][3]));
                acc2[1][0] = fmaf(a10, w0.x, fmaf(a11, w1.x, acc2[1][0]));
                acc2[1][1] = fmaf(a10, w0.y, fmaf(a11, w1.y, acc2[1][1]));
                acc2[1][2] = fmaf(a10, w0.z, fmaf(a11, w1.z, acc2[1][2]));
                acc2[1][3] = fmaf(a10, w0.w, fmaf(a11, w1.w, acc2[1][3]));
            }
        }
        float4 ab = *(const float4*)&affb[j0];
        #pragma unroll
        for (int i = 0; i < 2; i++) {
            float4 r;
            r.x = acc2[i][0] + ab.x; r.y = acc2[i][1] + ab.y;
            r.z = acc2[i][2] + ab.z; r.w = acc2[i][3] + ab.w;
            *(float4*)&logits[(size_t)(tile * 32 + s0 + i) * 64 + j0] = r;
        }
    }
}

__global__ __launch_bounds__(256) void finalize(const int* __restrict__ users,
                                                const int* __restrict__ items,
                                                const int* __restrict__ map,
                                                const float* __restrict__ logits,
                                                float* __restrict__ out) {
    int wave = (blockIdx.x * 256 + threadIdx.x) >> 6;
    int lane = threadIdx.x & 63;
    if (wave >= B_EVAL) return;
    int cu = map[users[wave]];
    int ci = map[N_USERS + items[wave]];
    float p = logits[(size_t)cu * D + lane] * logits[(size_t)ci * D + lane];
    #pragma unroll
    for (int off = 32; off > 0; off >>= 1) p += __shfl_down(p, off);
    if (lane == 0) out[wave] = p;
}

extern "C" void kernel_launch(void* const* d_in, const int* in_sizes, int n_in,
                              void* d_out, int out_size, void* d_ws, size_t ws_size,
                              hipStream_t stream) {
    const int*   users = (const int*)d_in[0];
    const int*   items = (const int*)d_in[1];
    const int*   rows  = (const int*)d_in[2];
    const int*   cols  = (const int*)d_in[3];
    const float* vals  = (const float*)d_in[4];
    const float* uemb  = (const float*)d_in[5];
    const float* iemb  = (const float*)d_in[6];
    const float* Wrel  = (const float*)d_in[7];
    const float* brel  = (const float*)d_in[8];
    const float* affW  = (const float*)d_in[9];
    const float* affb  = (const float*)d_in[10];
    float* out = (float*)d_out;

    char* ws = (char*)d_ws;
    int*   map    = (int*)(ws + OFF_MAP);
    int*   cnt    = (int*)(ws + OFF_CNT);
    int*   cntsb  = (int*)(ws + OFF_CSB);
    int*   offs   = (int*)(ws + OFF_OFFS);
    uint2* recs   = (uint2*)(ws + OFF_RECS);
    unsigned short* agg = (unsigned short*)(ws + OFF_AGG);
    float* logits = (float*)(ws + OFF_LOG);

    (void)hipMemsetAsync(map, 0xFF, (size_t)N_NODES * sizeof(int), stream);  // map = -1
    (void)hipMemsetAsync(cnt, 0, sizeof(int), stream);
    (void)hipMemsetAsync(cntsb, 0, (size_t)NSB * sizeof(int), stream);

    build_map<<<(2 * B_EVAL + 255) / 256, 256, 0, stream>>>(users, items, map, cnt);
    count_sb<<<(TOTAL_EDGES + 255) / 256, 256, 0, stream>>>(rows, map, cntsb);
    scan_sb<<<1, 1024, 0, stream>>>(cntsb, offs);
    fill_records<<<(TOTAL_EDGES + 255) / 256, 256, 0, stream>>>(rows, cols, vals, map, offs, recs);
    gather_buckets<<<NBUCKET, 128, 0, stream>>>(recs, uemb, iemb, offs, cntsb, cnt, agg);
    dense_tile<<<1024, 256, 0, stream>>>(agg, Wrel, brel, affW, affb, cnt, logits);
    finalize<<<(B_EVAL * 64) / 256, 256, 0, stream>>>(users, items, map, logits, out);
}

// Round 9
// 662.973 us; speedup vs baseline: 1.6627x; 1.6627x over previous
//
#include <hip/hip_runtime.h>

#define N_USERS 100000
#define N_ITEMS 50000
#define N_NODES 150000
#define N_REL 5
#define NNZ 2000000
#define D 64
#define B_EVAL 16384
#define MAXSLOTS 32768
#define NBUCKET 16384                 /* bucket = ci>>1 : 2 slots x 5 rels = 10 bins */
#define NSTRIPE 8
#define NSB (NBUCKET * NSTRIPE)       /* 131072 stripe-bucket segments */
#define TOTAL_EDGES (N_REL * NNZ)     /* 10,000,000 */
#define RECCAP 2000000                /* passing edges ~1.94M (deterministic input) */

// -------- workspace layout (bytes) ----
// map:    int[150000]        @ 0
// cnt:    int                @ 600,064
// cntsb:  int[131072]        @ 600,320     (524 KB)
// offs:   int[131072]        @ 1,124,608   (524 KB)
// recs:   uint2[2,000,000]   @ 1,648,896   (16.0 MB)
// agg:    bf16[32768*320]    @ 17,648,896  (21.0 MB)
// logits: float[32768*64]    @ 1,648,896   (overlaps recs - dead after gather)
// total footprint: 38,620,416 B
#define OFF_MAP   0
#define OFF_CNT   600064
#define OFF_CSB   600320
#define OFF_OFFS  1124608
#define OFF_RECS  1648896
#define OFF_AGG   17648896
#define OFF_LOG   1648896

__device__ __forceinline__ unsigned short f2bf(float f) {   // RNE f32->bf16
    unsigned u = __float_as_uint(f);
    return (unsigned short)((u + 0x7FFFu + ((u >> 16) & 1u)) >> 16);
}
__device__ __forceinline__ float bflo(unsigned p) { return __uint_as_float(p << 16); }
__device__ __forceinline__ float bfhi(unsigned p) { return __uint_as_float(p & 0xFFFF0000u); }

__global__ __launch_bounds__(256) void build_map(const int* __restrict__ users,
                                                 const int* __restrict__ items,
                                                 int* __restrict__ map,
                                                 int* __restrict__ cnt) {
    int t = blockIdx.x * 256 + threadIdx.x;
    if (t >= 2 * B_EVAL) return;
    int node = (t < B_EVAL) ? users[t] : (N_USERS + items[t - B_EVAL]);
    if (atomicCAS(&map[node], -1, -2) == -1) {
        int idx = atomicAdd(cnt, 1);
        map[node] = idx;
    }
}

// Count per (stripe, bucket); stripe = blockIdx&7 matches fill_records' mapping
// exactly (same grid), so counts == fills per segment deterministically.
__global__ __launch_bounds__(256) void count_sb(const int* __restrict__ rows,
                                                const int* __restrict__ map,
                                                int* __restrict__ cntsb) {
    int gid = blockIdx.x * 256 + threadIdx.x;
    if (gid >= TOTAL_EDGES) return;
    int ci = map[rows[gid]];
    if (ci >= 0)
        atomicAdd(&cntsb[(blockIdx.x & 7) * NBUCKET + (ci >> 1)], 1);
}

// Exclusive scan of 131072 counts: one block, 128 elems/thread serial + Hillis-Steele.
__global__ __launch_bounds__(1024) void scan_sb(const int* __restrict__ cntsb,
                                                int* __restrict__ offs) {
    __shared__ int sh[1024];
    int t = threadIdx.x;
    int base = t * 128;
    int sum = 0;
    for (int i = 0; i < 128; i++) sum += cntsb[base + i];
    sh[t] = sum;
    __syncthreads();
    int acc = sum;
    for (int off = 1; off < 1024; off <<= 1) {
        int add = (t >= off) ? sh[t - off] : 0;
        __syncthreads();
        acc += add;
        sh[t] = acc;
        __syncthreads();
    }
    int run = acc - sum;                 // exclusive prefix of this thread's chunk
    for (int i = 0; i < 128; i++) {
        int v = cntsb[base + i];
        offs[base + i] = run;
        run += v;
    }
}

// Scatter into 128K append segments. Open-line working set = 16K lines (1 MB)
// per XCD -> record lines fill fast and write-combine in the local L2.
// Tag packs col (18b) | rel (3b @18) | slotLocal (1b @21).
__global__ __launch_bounds__(256) void fill_records(const int* __restrict__ rows,
                                                    const int* __restrict__ cols,
                                                    const float* __restrict__ vals,
                                                    const int* __restrict__ map,
                                                    int* __restrict__ offs,
                                                    uint2* __restrict__ recs) {
    int gid = blockIdx.x * 256 + threadIdx.x;
    if (gid >= TOTAL_EDGES) return;
    int ci = map[rows[gid]];
    if (ci < 0) return;
    int rel = gid / NNZ;
    int sb = (blockIdx.x & 7) * NBUCKET + (ci >> 1);
    int pos = atomicAdd(&offs[sb], 1);
    unsigned tag = (unsigned)cols[gid] | ((unsigned)rel << 18) | ((unsigned)(ci & 1) << 21);
    if (pos < RECCAP)
        recs[pos] = make_uint2(tag, __float_as_uint(vals[gid]));
}

// One block per bucket (2 slots), 2 waves. Each wave processes HALF of every
// run (no filtering, no scan amplification), accumulating into 10 registers
// (2 slots x 5 rels; wave-uniform branch). Quad loads issue all 4 emb loads
// before any accumulate -> 4-deep MLP. 2.5 KB LDS only for final reduction.
__global__ __launch_bounds__(128) void gather_pairs(const uint2* __restrict__ recs,
                                                    const float* __restrict__ uemb,
                                                    const float* __restrict__ iemb,
                                                    const int* __restrict__ offs,
                                                    const int* __restrict__ cntsb,
                                                    const int* __restrict__ cnt,
                                                    unsigned short* __restrict__ agg) {
    __shared__ float lds[10 * 64];
    int b = blockIdx.x;
    int tid = threadIdx.x;
    int lane = tid & 63;
    int w = tid >> 6;                  // 0 or 1
    int cval = *cnt;
    if (b * 2 >= cval) return;         // uniform across block

    float a0 = 0, a1 = 0, a2 = 0, a3 = 0, a4 = 0;
    float a5 = 0, a6 = 0, a7 = 0, a8 = 0, a9 = 0;

#define ACC(x, v) { unsigned ix = ((x) >> 18) & 15u;                          \
    if      (ix == 0u)  a0 += (v); else if (ix == 1u)  a1 += (v);             \
    else if (ix == 2u)  a2 += (v); else if (ix == 3u)  a3 += (v);             \
    else if (ix == 4u)  a4 += (v); else if (ix == 8u)  a5 += (v);             \
    else if (ix == 9u)  a6 += (v); else if (ix == 10u) a7 += (v);             \
    else if (ix == 11u) a8 += (v); else                a9 += (v); }

    for (int s = 0; s < NSTRIPE; s++) {
        int sg = s * NBUCKET + b;
        int endf = offs[sg];           // post-fill: segment end
        int c = cntsb[sg];
        int start = endf - c;
        int half = c >> 1;
        int e  = w ? (start + half) : start;
        int hi = w ? endf : (start + half);
        for (; e + 4 <= hi; e += 4) {
            uint2 r0 = recs[e], r1 = recs[e + 1], r2 = recs[e + 2], r3 = recs[e + 3];
            unsigned c0 = r0.x & 0x3FFFFu, c1 = r1.x & 0x3FFFFu;
            unsigned c2 = r2.x & 0x3FFFFu, c3 = r3.x & 0x3FFFFu;
            const float* p0 = (c0 < N_USERS) ? uemb + (size_t)c0 * D : iemb + (size_t)(c0 - N_USERS) * D;
            const float* p1 = (c1 < N_USERS) ? uemb + (size_t)c1 * D : iemb + (size_t)(c1 - N_USERS) * D;
            const float* p2 = (c2 < N_USERS) ? uemb + (size_t)c2 * D : iemb + (size_t)(c2 - N_USERS) * D;
            const float* p3 = (c3 < N_USERS) ? uemb + (size_t)c3 * D : iemb + (size_t)(c3 - N_USERS) * D;
            float e0 = p0[lane], e1 = p1[lane], e2 = p2[lane], e3 = p3[lane];
            float v0 = __uint_as_float(r0.y) * e0;
            float v1 = __uint_as_float(r1.y) * e1;
            float v2 = __uint_as_float(r2.y) * e2;
            float v3 = __uint_as_float(r3.y) * e3;
            ACC(r0.x, v0); ACC(r1.x, v1); ACC(r2.x, v2); ACC(r3.x, v3);
        }
        for (; e < hi; e++) {
            uint2 r = recs[e];
            unsigned c0 = r.x & 0x3FFFFu;
            const float* p = (c0 < N_USERS) ? uemb + (size_t)c0 * D : iemb + (size_t)(c0 - N_USERS) * D;
            float v = __uint_as_float(r.y) * p[lane];
            ACC(r.x, v);
        }
    }
#undef ACC

    if (w == 0) {
        lds[0 * 64 + lane] = a0; lds[1 * 64 + lane] = a1; lds[2 * 64 + lane] = a2;
        lds[3 * 64 + lane] = a3; lds[4 * 64 + lane] = a4; lds[5 * 64 + lane] = a5;
        lds[6 * 64 + lane] = a6; lds[7 * 64 + lane] = a7; lds[8 * 64 + lane] = a8;
        lds[9 * 64 + lane] = a9;
    }
    __syncthreads();
    if (w == 1) {
        unsigned short* out = agg + (size_t)(b * 2) * 320;   // 2 slots x 5 rels x 64
        out[0 * 64 + lane] = f2bf(a0 + lds[0 * 64 + lane]);
        out[1 * 64 + lane] = f2bf(a1 + lds[1 * 64 + lane]);
        out[2 * 64 + lane] = f2bf(a2 + lds[2 * 64 + lane]);
        out[3 * 64 + lane] = f2bf(a3 + lds[3 * 64 + lane]);
        out[4 * 64 + lane] = f2bf(a4 + lds[4 * 64 + lane]);
        out[5 * 64 + lane] = f2bf(a5 + lds[5 * 64 + lane]);
        out[6 * 64 + lane] = f2bf(a6 + lds[6 * 64 + lane]);
        out[7 * 64 + lane] = f2bf(a7 + lds[7 * 64 + lane]);
        out[8 * 64 + lane] = f2bf(a8 + lds[8 * 64 + lane]);
        out[9 * 64 + lane] = f2bf(a9 + lds[9 * 64 + lane]);
    }
}

// LDS-tiled fused dense: 32 slots/block, 256 threads, 2x4 register tile/thread.
__global__ __launch_bounds__(256) void dense_tile(const unsigned short* __restrict__ agg,
                                                  const float* __restrict__ Wrel,
                                                  const float* __restrict__ brel,
                                                  const float* __restrict__ affW,
                                                  const float* __restrict__ affb,
                                                  const int* __restrict__ cnt,
                                                  float* __restrict__ logits) {
    __shared__ __align__(16) unsigned short shA[32][328];
    __shared__ __align__(16) unsigned short shM1[32][328];
    __shared__ __align__(16) float shW[64][68];

    int tid = threadIdx.x;
    int ty = tid >> 4, tx = tid & 15;
    int s0 = ty * 2;
    int j0 = tx * 4;
    int cval = *cnt;

    for (int tile = blockIdx.x; tile * 32 < cval; tile += gridDim.x) {
        __syncthreads();
        {
            const uint4* src = (const uint4*)(agg + (size_t)tile * 32 * 320);
            #pragma unroll
            for (int i = 0; i < 5; i++) {
                int idx = tid + i * 256;
                int p = idx * 8;
                int row = p / 320, col = p % 320;
                *(uint4*)&shA[row][col] = src[idx];
            }
        }
        #pragma unroll
        for (int k = 0; k < N_REL; k++) {
            __syncthreads();
            const float4* wsrc = (const float4*)(Wrel + (size_t)k * 4096);
            #pragma unroll
            for (int i = 0; i < 4; i++) {
                int idx = tid + i * 256;
                *(float4*)&shW[idx >> 4][(idx & 15) * 4] = wsrc[idx];
            }
            __syncthreads();
            float acc[2][4];
            #pragma unroll
            for (int jj = 0; jj < 4; jj++) {
                float b = brel[k * 64 + j0 + jj];
                acc[0][jj] = b; acc[1][jj] = b;
            }
            for (int d = 0; d < 64; d += 2) {
                unsigned pa0 = *(const unsigned*)&shA[s0][k * 64 + d];
                unsigned pa1 = *(const unsigned*)&shA[s0 + 1][k * 64 + d];
                float4 w0 = *(const float4*)&shW[d][j0];
                float4 w1 = *(const float4*)&shW[d + 1][j0];
                float a00 = bflo(pa0), a01 = bfhi(pa0);
                float a10 = bflo(pa1), a11 = bfhi(pa1);
                acc[0][0] = fmaf(a00, w0.x, fmaf(a01, w1.x, acc[0][0]));
                acc[0][1] = fmaf(a00, w0.y, fmaf(a01, w1.y, acc[0][1]));
                acc[0][2] = fmaf(a00, w0.z, fmaf(a01, w1.z, acc[0][2]));
                acc[0][3] = fmaf(a00, w0.w, fmaf(a01, w1.w, acc[0][3]));
                acc[1][0] = fmaf(a10, w0.x, fmaf(a11, w1.x, acc[1][0]));
                acc[1][1] = fmaf(a10, w0.y, fmaf(a11, w1.y, acc[1][1]));
                acc[1][2] = fmaf(a10, w0.z, fmaf(a11, w1.z, acc[1][2]));
                acc[1][3] = fmaf(a10, w0.w, fmaf(a11, w1.w, acc[1][3]));
            }
            #pragma unroll
            for (int i = 0; i < 2; i++) {
                #pragma unroll
                for (int jj = 0; jj < 4; jj++) {
                    float v = acc[i][jj];
                    acc[i][jj] = (v > 0.0f) ? v : 0.2f * v;   // leaky_relu 0.2
                }
                unsigned lo = (unsigned)f2bf(acc[i][0]) | ((unsigned)f2bf(acc[i][1]) << 16);
                unsigned hi = (unsigned)f2bf(acc[i][2]) | ((unsigned)f2bf(acc[i][3]) << 16);
                *(uint2*)&shM1[s0 + i][k * 64 + j0] = make_uint2(lo, hi);
            }
        }
        float acc2[2][4] = {{0,0,0,0},{0,0,0,0}};
        #pragma unroll
        for (int c = 0; c < N_REL; c++) {
            __syncthreads();
            const float4* wsrc = (const float4*)(affW + (size_t)c * 4096);
            #pragma unroll
            for (int i = 0; i < 4; i++) {
                int idx = tid + i * 256;
                *(float4*)&shW[idx >> 4][(idx & 15) * 4] = wsrc[idx];
            }
            __syncthreads();
            for (int dd = 0; dd < 64; dd += 2) {
                unsigned m0 = *(const unsigned*)&shM1[s0][c * 64 + dd];
                unsigned m1 = *(const unsigned*)&shM1[s0 + 1][c * 64 + dd];
                float4 w0 = *(const float4*)&shW[dd][j0];
                float4 w1 = *(const float4*)&shW[dd + 1][j0];
                float a00 = bflo(m0), a01 = bfhi(m0);
                float a10 = bflo(m1), a11 = bfhi(m1);
                acc2[0][0] = fmaf(a00, w0.x, fmaf(a01, w1.x, acc2[0][0]));
                acc2[0][1] = fmaf(a00, w0.y, fmaf(a01, w1.y, acc2[0][1]));
                acc2[0][2] = fmaf(a00, w0.z, fmaf(a01, w1.z, acc2[0][2]));
                acc2[0][3] = fmaf(a00, w0.w, fmaf(a01, w1.w, acc2[0][3]));
                acc2[1][0] = fmaf(a10, w0.x, fmaf(a11, w1.x, acc2[1][0]));
                acc2[1][1] = fmaf(a10, w0.y, fmaf(a11, w1.y, acc2[1][1]));
                acc2[1][2] = fmaf(a10, w0.z, fmaf(a11, w1.z, acc2[1][2]));
                acc2[1][3] = fmaf(a10, w0.w, fmaf(a11, w1.w, acc2[1][3]));
            }
        }
        float4 ab = *(const float4*)&affb[j0];
        #pragma unroll
        for (int i = 0; i < 2; i++) {
            float4 r;
            r.x = acc2[i][0] + ab.x; r.y = acc2[i][1] + ab.y;
            r.z = acc2[i][2] + ab.z; r.w = acc2[i][3] + ab.w;
            *(float4*)&logits[(size_t)(tile * 32 + s0 + i) * 64 + j0] = r;
        }
    }
}

__global__ __launch_bounds__(256) void finalize(const int* __restrict__ users,
                                                const int* __restrict__ items,
                                                const int* __restrict__ map,
                                                const float* __restrict__ logits,
                                                float* __restrict__ out) {
    int wave = (blockIdx.x * 256 + threadIdx.x) >> 6;
    int lane = threadIdx.x & 63;
    if (wave >= B_EVAL) return;
    int cu = map[users[wave]];
    int ci = map[N_USERS + items[wave]];
    float p = logits[(size_t)cu * D + lane] * logits[(size_t)ci * D + lane];
    #pragma unroll
    for (int off = 32; off > 0; off >>= 1) p += __shfl_down(p, off);
    if (lane == 0) out[wave] = p;
}

extern "C" void kernel_launch(void* const* d_in, const int* in_sizes, int n_in,
                              void* d_out, int out_size, void* d_ws, size_t ws_size,
                              hipStream_t stream) {
    const int*   users = (const int*)d_in[0];
    const int*   items = (const int*)d_in[1];
    const int*   rows  = (const int*)d_in[2];
    const int*   cols  = (const int*)d_in[3];
    const float* vals  = (const float*)d_in[4];
    const float* uemb  = (const float*)d_in[5];
    const float* iemb  = (const float*)d_in[6];
    const float* Wrel  = (const float*)d_in[7];
    const float* brel  = (const float*)d_in[8];
    const float* affW  = (const float*)d_in[9];
    const float* affb  = (const float*)d_in[10];
    float* out = (float*)d_out;

    char* ws = (char*)d_ws;
    int*   map    = (int*)(ws + OFF_MAP);
    int*   cnt    = (int*)(ws + OFF_CNT);
    int*   cntsb  = (int*)(ws + OFF_CSB);
    int*   offs   = (int*)(ws + OFF_OFFS);
    uint2* recs   = (uint2*)(ws + OFF_RECS);
    unsigned short* agg = (unsigned short*)(ws + OFF_AGG);
    float* logits = (float*)(ws + OFF_LOG);

    (void)hipMemsetAsync(map, 0xFF, (size_t)N_NODES * sizeof(int), stream);  // map = -1
    (void)hipMemsetAsync(cnt, 0, sizeof(int), stream);
    (void)hipMemsetAsync(cntsb, 0, (size_t)NSB * sizeof(int), stream);

    build_map<<<(2 * B_EVAL + 255) / 256, 256, 0, stream>>>(users, items, map, cnt);
    count_sb<<<(TOTAL_EDGES + 255) / 256, 256, 0, stream>>>(rows, map, cntsb);
    scan_sb<<<1, 1024, 0, stream>>>(cntsb, offs);
    fill_records<<<(TOTAL_EDGES + 255) / 256, 256, 0, stream>>>(rows, cols, vals, map, offs, recs);
    gather_pairs<<<NBUCKET, 128, 0, stream>>>(recs, uemb, iemb, offs, cntsb, cnt, agg);
    dense_tile<<<1024, 256, 0, stream>>>(agg, Wrel, brel, affW, affb, cnt, logits);
    finalize<<<(B_EVAL * 64) / 256, 256, 0, stream>>>(users, items, map, logits, out);
}

// Round 10
// 619.040 us; speedup vs baseline: 1.7807x; 1.0710x over previous
//
#include <hip/hip_runtime.h>

#define N_USERS 100000
#define N_ITEMS 50000
#define N_NODES 150000
#define N_REL 5
#define NNZ 2000000
#define D 64
#define B_EVAL 16384
#define MAXSLOTS 32768
#define NBUCKET 16384                 /* bucket = ci>>1 : 2 slots */
#define NSTRIPE 8
#define NSBR (NSTRIPE * NBUCKET * N_REL)   /* 655,360 segments (stripe,bucket,rel) */
#define SCAN_BLOCKS (NSBR / 1024)          /* 640 */
#define TOTAL_EDGES (N_REL * NNZ)          /* 10,000,000 */
#define RECCAP 2000000                     /* passing edges ~1.94M (deterministic) */

// -------- workspace layout (bytes) ----
// map:    int[150000]        @ 0
// cnt:    int                @ 600,064
// cnts:   int[655360]        @ 600,320     (2.62 MB)
// offs:   int[655360]        @ 3,221,760   (2.62 MB)
// bsum:   int[640]           @ 5,843,200
// bexcl:  int[640]           @ 5,845,760
// recs:   uint2[2,000,000]   @ 5,848,320   (16.0 MB)
// agg:    bf16[32768*320]    @ 21,848,320  (21.0 MB)
// logits: float[32768*64]    @ 5,848,320   (overlaps recs - dead after gather)
// total footprint: 42,819,840 B
#define OFF_MAP   0
#define OFF_CNT   600064
#define OFF_CNTS  600320
#define OFF_OFFS  3221760
#define OFF_BSUM  5843200
#define OFF_BEXCL 5845760
#define OFF_RECS  5848320
#define OFF_AGG   21848320
#define OFF_LOG   5848320

__device__ __forceinline__ unsigned short f2bf(float f) {   // RNE f32->bf16
    unsigned u = __float_as_uint(f);
    return (unsigned short)((u + 0x7FFFu + ((u >> 16) & 1u)) >> 16);
}
__device__ __forceinline__ float bflo(unsigned p) { return __uint_as_float(p << 16); }
__device__ __forceinline__ float bfhi(unsigned p) { return __uint_as_float(p & 0xFFFF0000u); }

__global__ __launch_bounds__(256) void build_map(const int* __restrict__ users,
                                                 const int* __restrict__ items,
                                                 int* __restrict__ map,
                                                 int* __restrict__ cnt) {
    int t = blockIdx.x * 256 + threadIdx.x;
    if (t >= 2 * B_EVAL) return;
    int node = (t < B_EVAL) ? users[t] : (N_USERS + items[t - B_EVAL]);
    if (atomicCAS(&map[node], -1, -2) == -1) {
        int idx = atomicAdd(cnt, 1);
        map[node] = idx;
    }
}

// Count per (stripe, bucket, rel). Key derived identically in fill_records
// (same 10M-thread launch geometry), so counts == fills per segment.
__global__ __launch_bounds__(256) void count_sbr(const int* __restrict__ rows,
                                                 const int* __restrict__ map,
                                                 int* __restrict__ cnts) {
    int gid = blockIdx.x * 256 + threadIdx.x;
    if (gid >= TOTAL_EDGES) return;
    int ci = map[rows[gid]];
    if (ci < 0) return;
    int rel = gid / NNZ;
    atomicAdd(&cnts[((blockIdx.x & 7) * NBUCKET + (ci >> 1)) * N_REL + rel], 1);
}

__global__ __launch_bounds__(1024) void scan_blocks(const int* __restrict__ cnts,
                                                    int* __restrict__ offs,
                                                    int* __restrict__ bsum) {
    __shared__ int sh[1024];
    int t = threadIdx.x;
    int g = blockIdx.x * 1024 + t;
    int v = cnts[g];
    sh[t] = v;
    __syncthreads();
    int acc = v;
    for (int off = 1; off < 1024; off <<= 1) {
        int add = (t >= off) ? sh[t - off] : 0;
        __syncthreads();
        acc += add;
        sh[t] = acc;
        __syncthreads();
    }
    offs[g] = acc - v;
    if (t == 1023) bsum[blockIdx.x] = acc;
}

__global__ __launch_bounds__(1024) void scan_tops(const int* __restrict__ bsum,
                                                  int* __restrict__ bexcl) {
    __shared__ int sh[1024];
    int t = threadIdx.x;
    int v = (t < SCAN_BLOCKS) ? bsum[t] : 0;
    sh[t] = v;
    __syncthreads();
    int acc = v;
    for (int off = 1; off < 1024; off <<= 1) {
        int add = (t >= off) ? sh[t - off] : 0;
        __syncthreads();
        acc += add;
        sh[t] = acc;
        __syncthreads();
    }
    if (t < SCAN_BLOCKS) bexcl[t] = acc - v;
}

__global__ __launch_bounds__(1024) void scan_add(int* __restrict__ offs,
                                                 const int* __restrict__ bexcl) {
    int g = blockIdx.x * 1024 + threadIdx.x;
    offs[g] += bexcl[blockIdx.x];
}

// Scatter into rel-partitioned append segments. Blocks dispatch ~in gid order,
// so only ~one rel's cursor slice is hot at a time: open record lines per XCD
// stay ~16K (1 MB, R9-proven write-combining regime), while records land
// rel-sorted within each (stripe,bucket) -> branch-free gather.
// Tag packs col (18b) | slotLocal (1b @18).
__global__ __launch_bounds__(256) void fill_records(const int* __restrict__ rows,
                                                    const int* __restrict__ cols,
                                                    const float* __restrict__ vals,
                                                    const int* __restrict__ map,
                                                    int* __restrict__ offs,
                                                    uint2* __restrict__ recs) {
    int gid = blockIdx.x * 256 + threadIdx.x;
    if (gid >= TOTAL_EDGES) return;
    int ci = map[rows[gid]];
    if (ci < 0) return;
    int rel = gid / NNZ;
    int idx = ((blockIdx.x & 7) * NBUCKET + (ci >> 1)) * N_REL + rel;
    int pos = atomicAdd(&offs[idx], 1);
    unsigned tag = (unsigned)cols[gid] | ((unsigned)(ci & 1) << 18);
    if (pos < RECCAP)
        recs[pos] = make_uint2(tag, __float_as_uint(vals[gid]));
}

// One wave per (bucket, rel): 81,920 short waves (R0-style TLP). Two
// accumulators (slot0/slot1 of the bucket), single-bit select -> ~20 VALU
// instr/record vs R9's ~64. Runs are direct (no select-chain).
__global__ __launch_bounds__(256) void gather_bins(const uint2* __restrict__ recs,
                                                   const float* __restrict__ uemb,
                                                   const float* __restrict__ iemb,
                                                   const int* __restrict__ offs,
                                                   const int* __restrict__ cnts,
                                                   const int* __restrict__ cnt,
                                                   unsigned short* __restrict__ agg) {
    int wid = (blockIdx.x * 256 + threadIdx.x) >> 6;
    int lane = threadIdx.x & 63;
    if (wid >= NBUCKET * N_REL) return;
    int b = wid / N_REL;
    int rel = wid - b * N_REL;
    if (b * 2 >= *cnt) return;

    int st[NSTRIPE], ln[NSTRIPE];
    #pragma unroll
    for (int s = 0; s < NSTRIPE; s++) {
        int ix = (s * NBUCKET + b) * N_REL + rel;
        int e = offs[ix];              // post-fill: segment end
        int c = cnts[ix];
        st[s] = e - c;
        ln[s] = c;
    }

    float a0 = 0.0f, a1 = 0.0f;
    #pragma unroll
    for (int s = 0; s < NSTRIPE; s++) {
        int e = st[s], hi = st[s] + ln[s];
        for (; e + 2 <= hi; e += 2) {
            uint2 r0 = recs[e], r1 = recs[e + 1];
            unsigned c0 = r0.x & 0x3FFFFu, c1 = r1.x & 0x3FFFFu;
            const float* p0 = (c0 < N_USERS) ? uemb + (size_t)c0 * D : iemb + (size_t)(c0 - N_USERS) * D;
            const float* p1 = (c1 < N_USERS) ? uemb + (size_t)c1 * D : iemb + (size_t)(c1 - N_USERS) * D;
            float v0 = __uint_as_float(r0.y) * p0[lane];
            float v1 = __uint_as_float(r1.y) * p1[lane];
            if (r0.x >> 18) a1 += v0; else a0 += v0;
            if (r1.x >> 18) a1 += v1; else a0 += v1;
        }
        if (e < hi) {
            uint2 r = recs[e];
            unsigned c0 = r.x & 0x3FFFFu;
            const float* p = (c0 < N_USERS) ? uemb + (size_t)c0 * D : iemb + (size_t)(c0 - N_USERS) * D;
            float v = __uint_as_float(r.y) * p[lane];
            if (r.x >> 18) a1 += v; else a0 += v;
        }
    }

    size_t o0 = (size_t)(b * 2) * 320 + (size_t)rel * 64 + lane;
    agg[o0] = f2bf(a0);
    agg[o0 + 320] = f2bf(a1);          // slot b*2+1
}

// LDS-tiled fused dense: 32 slots/block, 256 threads, 2x4 register tile/thread.
__global__ __launch_bounds__(256) void dense_tile(const unsigned short* __restrict__ agg,
                                                  const float* __restrict__ Wrel,
                                                  const float* __restrict__ brel,
                                                  const float* __restrict__ affW,
                                                  const float* __restrict__ affb,
                                                  const int* __restrict__ cnt,
                                                  float* __restrict__ logits) {
    __shared__ __align__(16) unsigned short shA[32][328];
    __shared__ __align__(16) unsigned short shM1[32][328];
    __shared__ __align__(16) float shW[64][68];

    int tid = threadIdx.x;
    int ty = tid >> 4, tx = tid & 15;
    int s0 = ty * 2;
    int j0 = tx * 4;
    int cval = *cnt;

    for (int tile = blockIdx.x; tile * 32 < cval; tile += gridDim.x) {
        __syncthreads();
        {
            const uint4* src = (const uint4*)(agg + (size_t)tile * 32 * 320);
            #pragma unroll
            for (int i = 0; i < 5; i++) {
                int idx = tid + i * 256;
                int p = idx * 8;
                int row = p / 320, col = p % 320;
                *(uint4*)&shA[row][col] = src[idx];
            }
        }
        #pragma unroll
        for (int k = 0; k < N_REL; k++) {
            __syncthreads();
            const float4* wsrc = (const float4*)(Wrel + (size_t)k * 4096);
            #pragma unroll
            for (int i = 0; i < 4; i++) {
                int idx = tid + i * 256;
                *(float4*)&shW[idx >> 4][(idx & 15) * 4] = wsrc[idx];
            }
            __syncthreads();
            float acc[2][4];
            #pragma unroll
            for (int jj = 0; jj < 4; jj++) {
                float b = brel[k * 64 + j0 + jj];
                acc[0][jj] = b; acc[1][jj] = b;
            }
            for (int d = 0; d < 64; d += 2) {
                unsigned pa0 = *(const unsigned*)&shA[s0][k * 64 + d];
                unsigned pa1 = *(const unsigned*)&shA[s0 + 1][k * 64 + d];
                float4 w0 = *(const float4*)&shW[d][j0];
                float4 w1 = *(const float4*)&shW[d + 1][j0];
                float a00 = bflo(pa0), a01 = bfhi(pa0);
                float a10 = bflo(pa1), a11 = bfhi(pa1);
                acc[0][0] = fmaf(a00, w0.x, fmaf(a01, w1.x, acc[0][0]));
                acc[0][1] = fmaf(a00, w0.y, fmaf(a01, w1.y, acc[0][1]));
                acc[0][2] = fmaf(a00, w0.z, fmaf(a01, w1.z, acc[0][2]));
                acc[0][3] = fmaf(a00, w0.w, fmaf(a01, w1.w, acc[0][3]));
                acc[1][0] = fmaf(a10, w0.x, fmaf(a11, w1.x, acc[1][0]));
                acc[1][1] = fmaf(a10, w0.y, fmaf(a11, w1.y, acc[1][1]));
                acc[1][2] = fmaf(a10, w0.z, fmaf(a11, w1.z, acc[1][2]));
                acc[1][3] = fmaf(a10, w0.w, fmaf(a11, w1.w, acc[1][3]));
            }
            #pragma unroll
            for (int i = 0; i < 2; i++) {
                #pragma unroll
                for (int jj = 0; jj < 4; jj++) {
                    float v = acc[i][jj];
                    acc[i][jj] = (v > 0.0f) ? v : 0.2f * v;   // leaky_relu 0.2
                }
                unsigned lo = (unsigned)f2bf(acc[i][0]) | ((unsigned)f2bf(acc[i][1]) << 16);
                unsigned hi = (unsigned)f2bf(acc[i][2]) | ((unsigned)f2bf(acc[i][3]) << 16);
                *(uint2*)&shM1[s0 + i][k * 64 + j0] = make_uint2(lo, hi);
            }
        }
        float acc2[2][4] = {{0,0,0,0},{0,0,0,0}};
        #pragma unroll
        for (int c = 0; c < N_REL; c++) {
            __syncthreads();
            const float4* wsrc = (const float4*)(affW + (size_t)c * 4096);
            #pragma unroll
            for (int i = 0; i < 4; i++) {
                int idx = tid + i * 256;
                *(float4*)&shW[idx >> 4][(idx & 15) * 4] = wsrc[idx];
            }
            __syncthreads();
            for (int dd = 0; dd < 64; dd += 2) {
                unsigned m0 = *(const unsigned*)&shM1[s0][c * 64 + dd];
                unsigned m1 = *(const unsigned*)&shM1[s0 + 1][c * 64 + dd];
                float4 w0 = *(const float4*)&shW[dd][j0];
                float4 w1 = *(const float4*)&shW[dd + 1][j0];
                float a00 = bflo(m0), a01 = bfhi(m0);
                float a10 = bflo(m1), a11 = bfhi(m1);
                acc2[0][0] = fmaf(a00, w0.x, fmaf(a01, w1.x, acc2[0][0]));
                acc2[0][1] = fmaf(a00, w0.y, fmaf(a01, w1.y, acc2[0][1]));
                acc2[0][2] = fmaf(a00, w0.z, fmaf(a01, w1.z, acc2[0][2]));
                acc2[0][3] = fmaf(a00, w0.w, fmaf(a01, w1.w, acc2[0][3]));
                acc2[1][0] = fmaf(a10, w0.x, fmaf(a11, w1.x, acc2[1][0]));
                acc2[1][1] = fmaf(a10, w0.y, fmaf(a11, w1.y, acc2[1][1]));
                acc2[1][2] = fmaf(a10, w0.z, fmaf(a11, w1.z, acc2[1][2]));
                acc2[1][3] = fmaf(a10, w0.w, fmaf(a11, w1.w, acc2[1][3]));
            }
        }
        float4 ab = *(const float4*)&affb[j0];
        #pragma unroll
        for (int i = 0; i < 2; i++) {
            float4 r;
            r.x = acc2[i][0] + ab.x; r.y = acc2[i][1] + ab.y;
            r.z = acc2[i][2] + ab.z; r.w = acc2[i][3] + ab.w;
            *(float4*)&logits[(size_t)(tile * 32 + s0 + i) * 64 + j0] = r;
        }
    }
}

__global__ __launch_bounds__(256) void finalize(const int* __restrict__ users,
                                                const int* __restrict__ items,
                                                const int* __restrict__ map,
                                                const float* __restrict__ logits,
                                                float* __restrict__ out) {
    int wave = (blockIdx.x * 256 + threadIdx.x) >> 6;
    int lane = threadIdx.x & 63;
    if (wave >= B_EVAL) return;
    int cu = map[users[wave]];
    int ci = map[N_USERS + items[wave]];
    float p = logits[(size_t)cu * D + lane] * logits[(size_t)ci * D + lane];
    #pragma unroll
    for (int off = 32; off > 0; off >>= 1) p += __shfl_down(p, off);
    if (lane == 0) out[wave] = p;
}

extern "C" void kernel_launch(void* const* d_in, const int* in_sizes, int n_in,
                              void* d_out, int out_size, void* d_ws, size_t ws_size,
                              hipStream_t stream) {
    const int*   users = (const int*)d_in[0];
    const int*   items = (const int*)d_in[1];
    const int*   rows  = (const int*)d_in[2];
    const int*   cols  = (const int*)d_in[3];
    const float* vals  = (const float*)d_in[4];
    const float* uemb  = (const float*)d_in[5];
    const float* iemb  = (const float*)d_in[6];
    const float* Wrel  = (const float*)d_in[7];
    const float* brel  = (const float*)d_in[8];
    const float* affW  = (const float*)d_in[9];
    const float* affb  = (const float*)d_in[10];
    float* out = (float*)d_out;

    char* ws = (char*)d_ws;
    int*   map    = (int*)(ws + OFF_MAP);
    int*   cnt    = (int*)(ws + OFF_CNT);
    int*   cnts   = (int*)(ws + OFF_CNTS);
    int*   offs   = (int*)(ws + OFF_OFFS);
    int*   bsum   = (int*)(ws + OFF_BSUM);
    int*   bexcl  = (int*)(ws + OFF_BEXCL);
    uint2* recs   = (uint2*)(ws + OFF_RECS);
    unsigned short* agg = (unsigned short*)(ws + OFF_AGG);
    float* logits = (float*)(ws + OFF_LOG);

    (void)hipMemsetAsync(map, 0xFF, (size_t)N_NODES * sizeof(int), stream);  // map = -1
    (void)hipMemsetAsync(cnt, 0, sizeof(int), stream);
    (void)hipMemsetAsync(cnts, 0, (size_t)NSBR * sizeof(int), stream);

    build_map<<<(2 * B_EVAL + 255) / 256, 256, 0, stream>>>(users, items, map, cnt);
    count_sbr<<<(TOTAL_EDGES + 255) / 256, 256, 0, stream>>>(rows, map, cnts);
    scan_blocks<<<SCAN_BLOCKS, 1024, 0, stream>>>(cnts, offs, bsum);
    scan_tops<<<1, 1024, 0, stream>>>(bsum, bexcl);
    scan_add<<<SCAN_BLOCKS, 1024, 0, stream>>>(offs, bexcl);
    fill_records<<<(TOTAL_EDGES + 255) / 256, 256, 0, stream>>>(rows, cols, vals, map, offs, recs);
    gather_bins<<<(NBUCKET * N_REL * 64) / 256, 256, 0, stream>>>(recs, uemb, iemb, offs, cnts, cnt, agg);
    dense_tile<<<1024, 256, 0, stream>>>(agg, Wrel, brel, affW, affb, cnt, logits);
    finalize<<<(B_EVAL * 64) / 256, 256, 0, stream>>>(users, items, map, logits, out);
}

// Round 11
// 543.253 us; speedup vs baseline: 2.0291x; 1.1395x over previous
//
#include <hip/hip_runtime.h>

#define N_USERS 100000
#define N_ITEMS 50000
#define N_NODES 150000
#define N_REL 5
#define NNZ 2000000
#define D 64
#define B_EVAL 16384
#define MAXSLOTS 32768
#define NCB 256                        /* coarse buckets: cb = slot>>7 */
#define BCAP 10240                     /* records per bucket region (avg 7578, +30 sigma) */
#define FINE_PER_B 640                 /* 128 slots x 5 rels */
#define NFINE (NCB * FINE_PER_B)       /* 163840 fine bins */
#define EDGES_PER_BLOCK 16384
#define FILL_BLOCKS 611                /* ceil(10M / 16384) */
#define TOTAL_EDGES (N_REL * NNZ)      /* 10,000,000 */

// -------- workspace layout (bytes) ----
// map:       int[150000]            @ 0
// cnt:       int                    @ 600,064
// cursors:   int[256]               @ 600,320
// fineStart: int[163840]            @ 601,344
// fineCnt:   int[163840]            @ 1,256,704
// recs:      uint2[256*10240]       @ 1,912,064   (21.0 MB)
// sorted:    uint2[256*10240]       @ 22,883,584  (21.0 MB)
// agg:       bf16[32768*320]        @ 1,912,064   (overlay recs - dead after sort)
// logits:    f32[32768*64]          @ 22,883,584  (overlay sorted - dead after gather)
// total footprint: 43,855,104 B (< 48 MB proven)
#define OFF_MAP   0
#define OFF_CNT   600064
#define OFF_CUR   600320
#define OFF_FST   601344
#define OFF_FCN   1256704
#define OFF_RECS  1912064
#define OFF_SORT  22883584
#define OFF_AGG   1912064
#define OFF_LOG   22883584

__device__ __forceinline__ unsigned short f2bf(float f) {   // RNE f32->bf16
    unsigned u = __float_as_uint(f);
    return (unsigned short)((u + 0x7FFFu + ((u >> 16) & 1u)) >> 16);
}
__device__ __forceinline__ float bflo(unsigned p) { return __uint_as_float(p << 16); }
__device__ __forceinline__ float bfhi(unsigned p) { return __uint_as_float(p & 0xFFFF0000u); }

__global__ __launch_bounds__(256) void build_map(const int* __restrict__ users,
                                                 const int* __restrict__ items,
                                                 int* __restrict__ map,
                                                 int* __restrict__ cnt) {
    int t = blockIdx.x * 256 + threadIdx.x;
    if (t >= 2 * B_EVAL) return;
    int node = (t < B_EVAL) ? users[t] : (N_USERS + items[t - B_EVAL]);
    if (atomicCAS(&map[node], -1, -2) == -1) {
        int idx = atomicAdd(cnt, 1);
        map[node] = idx;
    }
}

__global__ __launch_bounds__(256) void init_cursors(int* __restrict__ cursors) {
    cursors[threadIdx.x] = threadIdx.x * BCAP;   // fixed bucket regions -> no scan needed
}

// Each block owns 16K contiguous edges. Pass 1 LDS-counts 256 coarse buckets;
// one global atomicAdd per (block,bucket) reserves a CONTIGUOUS chunk; pass 2
// writes records contiguously (~12-record runs -> full-line writes, no granule
// amplification). rows/map re-read in pass 2 hit L2 (64KB window / 600KB map).
// Tag: col (18b) | fine (10b @18), fine = (slot&127)*5 + rel.
__global__ __launch_bounds__(256) void fill_coarse(const int* __restrict__ rows,
                                                   const int* __restrict__ cols,
                                                   const float* __restrict__ vals,
                                                   const int* __restrict__ map,
                                                   int* __restrict__ cursors,
                                                   uint2* __restrict__ recs) {
    __shared__ int cnt1[NCB], cnt2[NCB], base[NCB];
    int tid = threadIdx.x;
    int e0 = blockIdx.x * EDGES_PER_BLOCK;
    int nE = TOTAL_EDGES - e0;
    if (nE > EDGES_PER_BLOCK) nE = EDGES_PER_BLOCK;
    if (nE <= 0) return;
    cnt1[tid] = 0; cnt2[tid] = 0;
    __syncthreads();
    for (int i = tid; i < nE; i += 256) {
        int ci = map[rows[e0 + i]];
        if (ci >= 0) atomicAdd(&cnt1[ci >> 7], 1);
    }
    __syncthreads();
    if (cnt1[tid] > 0) base[tid] = atomicAdd(&cursors[tid], cnt1[tid]);
    __syncthreads();
    for (int i = tid; i < nE; i += 256) {
        int gid = e0 + i;
        int ci = map[rows[gid]];
        if (ci < 0) continue;
        int cb = ci >> 7;
        int r = atomicAdd(&cnt2[cb], 1);
        int pos = base[cb] + r;
        if (pos < (cb + 1) * BCAP) {   // overflow guard (statistically impossible)
            int rel = gid / NNZ;
            unsigned fine = (unsigned)((ci & 127) * N_REL + rel);
            recs[pos] = make_uint2((unsigned)cols[gid] | (fine << 18), __float_as_uint(vals[gid]));
        }
    }
}

// One block per coarse bucket: count 640 fine bins in LDS, LDS scan, place all
// records at sorted positions in LDS (80KB), stream out coalesced full lines.
// Emits fineStart/fineCnt tables for the gather.
__global__ __launch_bounds__(256) void sort_bucket(const uint2* __restrict__ recs,
                                                   const int* __restrict__ cursors,
                                                   uint2* __restrict__ sorted,
                                                   int* __restrict__ fineStart,
                                                   int* __restrict__ fineCnt) {
    __shared__ int cnt[FINE_PER_B], scn[FINE_PER_B], cnt2[FINE_PER_B];
    __shared__ int tscan[256];
    __shared__ uint2 srt[BCAP];
    int cb = blockIdx.x, tid = threadIdx.x;
    int rbase = cb * BCAP;
    int n = cursors[cb] - rbase;
    if (n > BCAP) n = BCAP;
    for (int i = tid; i < FINE_PER_B; i += 256) { cnt[i] = 0; cnt2[i] = 0; }
    __syncthreads();
    for (int i = tid; i < n; i += 256) atomicAdd(&cnt[recs[rbase + i].x >> 18], 1);
    __syncthreads();
    // scan 640 bins: 3 bins/thread serial + Hillis-Steele over 256 thread sums
    int b0 = tid * 3;
    int c0 = (b0     < FINE_PER_B) ? cnt[b0]     : 0;
    int c1 = (b0 + 1 < FINE_PER_B) ? cnt[b0 + 1] : 0;
    int c2 = (b0 + 2 < FINE_PER_B) ? cnt[b0 + 2] : 0;
    int tsum = c0 + c1 + c2;
    tscan[tid] = tsum;
    __syncthreads();
    int acc = tsum;
    for (int off = 1; off < 256; off <<= 1) {
        int add = (tid >= off) ? tscan[tid - off] : 0;
        __syncthreads();
        acc += add;
        tscan[tid] = acc;
        __syncthreads();
    }
    int ex = acc - tsum;
    if (b0     < FINE_PER_B) scn[b0]     = ex;
    if (b0 + 1 < FINE_PER_B) scn[b0 + 1] = ex + c0;
    if (b0 + 2 < FINE_PER_B) scn[b0 + 2] = ex + c0 + c1;
    __syncthreads();
    for (int i = tid; i < n; i += 256) {
        uint2 r = recs[rbase + i];
        unsigned f = r.x >> 18;
        int p = scn[f] + atomicAdd(&cnt2[f], 1);
        srt[p] = make_uint2(r.x & 0x3FFFFu, r.y);   // strip tag: col only
    }
    __syncthreads();
    for (int i = tid; i < n; i += 256) sorted[rbase + i] = srt[i];
    for (int i = tid; i < FINE_PER_B; i += 256) {
        fineStart[cb * FINE_PER_B + i] = rbase + scn[i];
        fineCnt[cb * FINE_PER_B + i]   = cnt[i];
    }
}

// One wave per exact (slot, rel) run: single accumulator, zero tag logic,
// 2-deep MLP on the record->embedding chase. 164K short waves (R0-style TLP).
__global__ __launch_bounds__(256) void gather_fine(const uint2* __restrict__ sorted,
                                                   const float* __restrict__ uemb,
                                                   const float* __restrict__ iemb,
                                                   const int* __restrict__ fineStart,
                                                   const int* __restrict__ fineCnt,
                                                   const int* __restrict__ cnt,
                                                   unsigned short* __restrict__ agg) {
    int wid = (blockIdx.x * 256 + threadIdx.x) >> 6;
    int lane = threadIdx.x & 63;
    if (wid >= NFINE) return;
    int cb = wid / FINE_PER_B;
    int f = wid - cb * FINE_PER_B;
    int sl = f / N_REL;
    int rel = f - sl * N_REL;
    int slot = cb * 128 + sl;
    if (slot >= *cnt) return;

    int st = fineStart[wid];
    int hi = st + fineCnt[wid];
    float a = 0.0f;
    int e = st;
    for (; e + 2 <= hi; e += 2) {
        uint2 r0 = sorted[e], r1 = sorted[e + 1];
        const float* p0 = (r0.x < N_USERS) ? uemb + (size_t)r0.x * D : iemb + (size_t)(r0.x - N_USERS) * D;
        const float* p1 = (r1.x < N_USERS) ? uemb + (size_t)r1.x * D : iemb + (size_t)(r1.x - N_USERS) * D;
        a = fmaf(__uint_as_float(r0.y), p0[lane], a);
        a = fmaf(__uint_as_float(r1.y), p1[lane], a);
    }
    if (e < hi) {
        uint2 r = sorted[e];
        const float* p = (r.x < N_USERS) ? uemb + (size_t)r.x * D : iemb + (size_t)(r.x - N_USERS) * D;
        a = fmaf(__uint_as_float(r.y), p[lane], a);
    }
    agg[(size_t)slot * 320 + (size_t)rel * 64 + lane] = f2bf(a);
}

// LDS-tiled fused dense: 32 slots/block, 256 threads, 2x4 register tile/thread.
__global__ __launch_bounds__(256) void dense_tile(const unsigned short* __restrict__ agg,
                                                  const float* __restrict__ Wrel,
                                                  const float* __restrict__ brel,
                                                  const float* __restrict__ affW,
                                                  const float* __restrict__ affb,
                                                  const int* __restrict__ cnt,
                                                  float* __restrict__ logits) {
    __shared__ __align__(16) unsigned short shA[32][328];
    __shared__ __align__(16) unsigned short shM1[32][328];
    __shared__ __align__(16) float shW[64][68];

    int tid = threadIdx.x;
    int ty = tid >> 4, tx = tid & 15;
    int s0 = ty * 2;
    int j0 = tx * 4;
    int cval = *cnt;

    for (int tile = blockIdx.x; tile * 32 < cval; tile += gridDim.x) {
        __syncthreads();
        {
            const uint4* src = (const uint4*)(agg + (size_t)tile * 32 * 320);
            #pragma unroll
            for (int i = 0; i < 5; i++) {
                int idx = tid + i * 256;
                int p = idx * 8;
                int row = p / 320, col = p % 320;
                *(uint4*)&shA[row][col] = src[idx];
            }
        }
        #pragma unroll
        for (int k = 0; k < N_REL; k++) {
            __syncthreads();
            const float4* wsrc = (const float4*)(Wrel + (size_t)k * 4096);
            #pragma unroll
            for (int i = 0; i < 4; i++) {
                int idx = tid + i * 256;
                *(float4*)&shW[idx >> 4][(idx & 15) * 4] = wsrc[idx];
            }
            __syncthreads();
            float acc[2][4];
            #pragma unroll
            for (int jj = 0; jj < 4; jj++) {
                float b = brel[k * 64 + j0 + jj];
                acc[0][jj] = b; acc[1][jj] = b;
            }
            for (int d = 0; d < 64; d += 2) {
                unsigned pa0 = *(const unsigned*)&shA[s0][k * 64 + d];
                unsigned pa1 = *(const unsigned*)&shA[s0 + 1][k * 64 + d];
                float4 w0 = *(const float4*)&shW[d][j0];
                float4 w1 = *(const float4*)&shW[d + 1][j0];
                float a00 = bflo(pa0), a01 = bfhi(pa0);
                float a10 = bflo(pa1), a11 = bfhi(pa1);
                acc[0][0] = fmaf(a00, w0.x, fmaf(a01, w1.x, acc[0][0]));
                acc[0][1] = fmaf(a00, w0.y, fmaf(a01, w1.y, acc[0][1]));
                acc[0][2] = fmaf(a00, w0.z, fmaf(a01, w1.z, acc[0][2]));
                acc[0][3] = fmaf(a00, w0.w, fmaf(a01, w1.w, acc[0][3]));
                acc[1][0] = fmaf(a10, w0.x, fmaf(a11, w1.x, acc[1][0]));
                acc[1][1] = fmaf(a10, w0.y, fmaf(a11, w1.y, acc[1][1]));
                acc[1][2] = fmaf(a10, w0.z, fmaf(a11, w1.z, acc[1][2]));
                acc[1][3] = fmaf(a10, w0.w, fmaf(a11, w1.w, acc[1][3]));
            }
            #pragma unroll
            for (int i = 0; i < 2; i++) {
                #pragma unroll
                for (int jj = 0; jj < 4; jj++) {
                    float v = acc[i][jj];
                    acc[i][jj] = (v > 0.0f) ? v : 0.2f * v;   // leaky_relu 0.2
                }
                unsigned lo = (unsigned)f2bf(acc[i][0]) | ((unsigned)f2bf(acc[i][1]) << 16);
                unsigned hi = (unsigned)f2bf(acc[i][2]) | ((unsigned)f2bf(acc[i][3]) << 16);
                *(uint2*)&shM1[s0 + i][k * 64 + j0] = make_uint2(lo, hi);
            }
        }
        float acc2[2][4] = {{0,0,0,0},{0,0,0,0}};
        #pragma unroll
        for (int c = 0; c < N_REL; c++) {
            __syncthreads();
            const float4* wsrc = (const float4*)(affW + (size_t)c * 4096);
            #pragma unroll
            for (int i = 0; i < 4; i++) {
                int idx = tid + i * 256;
                *(float4*)&shW[idx >> 4][(idx & 15) * 4] = wsrc[idx];
            }
            __syncthreads();
            for (int dd = 0; dd < 64; dd += 2) {
                unsigned m0 = *(const unsigned*)&shM1[s0][c * 64 + dd];
                unsigned m1 = *(const unsigned*)&shM1[s0 + 1][c * 64 + dd];
                float4 w0 = *(const float4*)&shW[dd][j0];
                float4 w1 = *(const float4*)&shW[dd + 1][j0];
                float a00 = bflo(m0), a01 = bfhi(m0);
                float a10 = bflo(m1), a11 = bfhi(m1);
                acc2[0][0] = fmaf(a00, w0.x, fmaf(a01, w1.x, acc2[0][0]));
                acc2[0][1] = fmaf(a00, w0.y, fmaf(a01, w1.y, acc2[0][1]));
                acc2[0][2] = fmaf(a00, w0.z, fmaf(a01, w1.z, acc2[0][2]));
                acc2[0][3] = fmaf(a00, w0.w, fmaf(a01, w1.w, acc2[0][3]));
                acc2[1][0] = fmaf(a10, w0.x, fmaf(a11, w1.x, acc2[1][0]));
                acc2[1][1] = fmaf(a10, w0.y, fmaf(a11, w1.y, acc2[1][1]));
                acc2[1][2] = fmaf(a10, w0.z, fmaf(a11, w1.z, acc2[1][2]));
                acc2[1][3] = fmaf(a10, w0.w, fmaf(a11, w1.w, acc2[1][3]));
            }
        }
        float4 ab = *(const float4*)&affb[j0];
        #pragma unroll
        for (int i = 0; i < 2; i++) {
            float4 r;
            r.x = acc2[i][0] + ab.x; r.y = acc2[i][1] + ab.y;
            r.z = acc2[i][2] + ab.z; r.w = acc2[i][3] + ab.w;
            *(float4*)&logits[(size_t)(tile * 32 + s0 + i) * 64 + j0] = r;
        }
    }
}

__global__ __launch_bounds__(256) void finalize(const int* __restrict__ users,
                                                const int* __restrict__ items,
                                                const int* __restrict__ map,
                                                const float* __restrict__ logits,
                                                float* __restrict__ out) {
    int wave = (blockIdx.x * 256 + threadIdx.x) >> 6;
    int lane = threadIdx.x & 63;
    if (wave >= B_EVAL) return;
    int cu = map[users[wave]];
    int ci = map[N_USERS + items[wave]];
    float p = logits[(size_t)cu * D + lane] * logits[(size_t)ci * D + lane];
    #pragma unroll
    for (int off = 32; off > 0; off >>= 1) p += __shfl_down(p, off);
    if (lane == 0) out[wave] = p;
}

extern "C" void kernel_launch(void* const* d_in, const int* in_sizes, int n_in,
                              void* d_out, int out_size, void* d_ws, size_t ws_size,
                              hipStream_t stream) {
    const int*   users = (const int*)d_in[0];
    const int*   items = (const int*)d_in[1];
    const int*   rows  = (const int*)d_in[2];
    const int*   cols  = (const int*)d_in[3];
    const float* vals  = (const float*)d_in[4];
    const float* uemb  = (const float*)d_in[5];
    const float* iemb  = (const float*)d_in[6];
    const float* Wrel  = (const float*)d_in[7];
    const float* brel  = (const float*)d_in[8];
    const float* affW  = (const float*)d_in[9];
    const float* affb  = (const float*)d_in[10];
    float* out = (float*)d_out;

    char* ws = (char*)d_ws;
    int*   map     = (int*)(ws + OFF_MAP);
    int*   cnt     = (int*)(ws + OFF_CNT);
    int*   cursors = (int*)(ws + OFF_CUR);
    int*   fineSt  = (int*)(ws + OFF_FST);
    int*   fineCn  = (int*)(ws + OFF_FCN);
    uint2* recs    = (uint2*)(ws + OFF_RECS);
    uint2* sorted  = (uint2*)(ws + OFF_SORT);
    unsigned short* agg = (unsigned short*)(ws + OFF_AGG);
    float* logits  = (float*)(ws + OFF_LOG);

    (void)hipMemsetAsync(map, 0xFF, (size_t)N_NODES * sizeof(int), stream);  // map = -1
    (void)hipMemsetAsync(cnt, 0, sizeof(int), stream);

    build_map<<<(2 * B_EVAL + 255) / 256, 256, 0, stream>>>(users, items, map, cnt);
    init_cursors<<<1, 256, 0, stream>>>(cursors);
    fill_coarse<<<FILL_BLOCKS, 256, 0, stream>>>(rows, cols, vals, map, cursors, recs);
    sort_bucket<<<NCB, 256, 0, stream>>>(recs, cursors, sorted, fineSt, fineCn);
    gather_fine<<<(NFINE * 64) / 256, 256, 0, stream>>>(sorted, uemb, iemb, fineSt, fineCn, cnt, agg);
    dense_tile<<<1024, 256, 0, stream>>>(agg, Wrel, brel, affW, affb, cnt, logits);
    finalize<<<(B_EVAL * 64) / 256, 256, 0, stream>>>(users, items, map, logits, out);
}

// Round 12
// 496.314 us; speedup vs baseline: 2.2210x; 1.0946x over previous
//
#include <hip/hip_runtime.h>

#define N_USERS 100000
#define N_ITEMS 50000
#define N_NODES 150000
#define N_REL 5
#define NNZ 2000000
#define D 64
#define B_EVAL 16384
#define MAXSLOTS 32768
#define NCB 256                        /* coarse buckets: cb = slot>>7 */
#define BCAP 10240                     /* records per bucket region (avg 7578) */
#define FINE_PER_B 640                 /* 128 slots x 5 rels */
#define NFINE (NCB * FINE_PER_B)       /* 163840 fine bins */
#define EDGES_PER_BLOCK 4096
#define FILL_BLOCKS 2442               /* ceil(10M / 4096) */
#define TOTAL_EDGES (N_REL * NNZ)      /* 10,000,000 */

// -------- workspace layout (bytes) ----
// map:       int[150000]            @ 0
// cnt:       int                    @ 600,064
// cursors:   int[256]               @ 600,320
// fineStart: int[163840]            @ 601,344
// fineCnt:   int[163840]            @ 1,256,704
// recs:      uint2[256*10240]       @ 1,912,064   (21.0 MB)
// sorted:    uint2[256*10240]       @ 22,883,584  (21.0 MB)
// agg:       bf16[32768*320]        @ 1,912,064   (overlay recs - dead after sort)
// logits:    f32[32768*64]          @ 22,883,584  (overlay sorted - dead after gather)
// total footprint: 43,855,104 B
#define OFF_MAP   0
#define OFF_CNT   600064
#define OFF_CUR   600320
#define OFF_FST   601344
#define OFF_FCN   1256704
#define OFF_RECS  1912064
#define OFF_SORT  22883584
#define OFF_AGG   1912064
#define OFF_LOG   22883584

__device__ __forceinline__ unsigned short f2bf(float f) {   // RNE f32->bf16
    unsigned u = __float_as_uint(f);
    return (unsigned short)((u + 0x7FFFu + ((u >> 16) & 1u)) >> 16);
}
__device__ __forceinline__ float bflo(unsigned p) { return __uint_as_float(p << 16); }
__device__ __forceinline__ float bfhi(unsigned p) { return __uint_as_float(p & 0xFFFF0000u); }

__global__ __launch_bounds__(256) void build_map(const int* __restrict__ users,
                                                 const int* __restrict__ items,
                                                 int* __restrict__ map,
                                                 int* __restrict__ cnt) {
    int t = blockIdx.x * 256 + threadIdx.x;
    if (t >= 2 * B_EVAL) return;
    int node = (t < B_EVAL) ? users[t] : (N_USERS + items[t - B_EVAL]);
    if (atomicCAS(&map[node], -1, -2) == -1) {
        int idx = atomicAdd(cnt, 1);
        map[node] = idx;
    }
}

__global__ __launch_bounds__(256) void init_cursors(int* __restrict__ cursors) {
    cursors[threadIdx.x] = threadIdx.x * BCAP;   // fixed bucket regions -> no scan needed
}

// Each block owns 4K contiguous edges (2442 blocks -> ~38 waves/CU offered:
// occupancy-capped, 4x the TLP of R11's 611-block version). Pass 1 LDS-counts
// 256 coarse buckets AND caches ci in LDS; one global atomicAdd per
// (block,bucket) reserves a contiguous chunk; pass 2 writes records
// contiguously from the LDS ci-cache (no second map walk).
// Tag: col (18b) | fine (10b @18), fine = (slot&127)*5 + rel.
__global__ __launch_bounds__(256) void fill_coarse(const int* __restrict__ rows,
                                                   const int* __restrict__ cols,
                                                   const float* __restrict__ vals,
                                                   const int* __restrict__ map,
                                                   int* __restrict__ cursors,
                                                   uint2* __restrict__ recs) {
    __shared__ int cnt1[NCB], cnt2[NCB], base[NCB];
    __shared__ short ciCache[EDGES_PER_BLOCK];   // 8 KB; ci in [-1, 32767]
    int tid = threadIdx.x;
    int e0 = blockIdx.x * EDGES_PER_BLOCK;
    int nE = TOTAL_EDGES - e0;
    if (nE > EDGES_PER_BLOCK) nE = EDGES_PER_BLOCK;
    if (nE <= 0) return;
    cnt1[tid] = 0; cnt2[tid] = 0;
    __syncthreads();
    for (int i = tid; i < nE; i += 256) {
        int ci = map[rows[e0 + i]];
        ciCache[i] = (short)ci;
        if (ci >= 0) atomicAdd(&cnt1[ci >> 7], 1);
    }
    __syncthreads();
    if (cnt1[tid] > 0) base[tid] = atomicAdd(&cursors[tid], cnt1[tid]);
    __syncthreads();
    for (int i = tid; i < nE; i += 256) {
        int ci = ciCache[i];
        if (ci < 0) continue;
        int gid = e0 + i;
        int cb = ci >> 7;
        int r = atomicAdd(&cnt2[cb], 1);
        int pos = base[cb] + r;
        if (pos < (cb + 1) * BCAP) {   // overflow guard (statistically impossible)
            int rel = gid / NNZ;
            unsigned fine = (unsigned)((ci & 127) * N_REL + rel);
            recs[pos] = make_uint2((unsigned)cols[gid] | (fine << 18), __float_as_uint(vals[gid]));
        }
    }
}

// One block per coarse bucket: count 640 fine bins in LDS, LDS scan, place all
// records at sorted positions in LDS (80KB), stream out coalesced full lines.
// Emits fineStart/fineCnt tables for the gather.
__global__ __launch_bounds__(256) void sort_bucket(const uint2* __restrict__ recs,
                                                   const int* __restrict__ cursors,
                                                   uint2* __restrict__ sorted,
                                                   int* __restrict__ fineStart,
                                                   int* __restrict__ fineCnt) {
    __shared__ int cnt[FINE_PER_B], scn[FINE_PER_B], cnt2[FINE_PER_B];
    __shared__ int tscan[256];
    __shared__ uint2 srt[BCAP];
    int cb = blockIdx.x, tid = threadIdx.x;
    int rbase = cb * BCAP;
    int n = cursors[cb] - rbase;
    if (n > BCAP) n = BCAP;
    for (int i = tid; i < FINE_PER_B; i += 256) { cnt[i] = 0; cnt2[i] = 0; }
    __syncthreads();
    for (int i = tid; i < n; i += 256) atomicAdd(&cnt[recs[rbase + i].x >> 18], 1);
    __syncthreads();
    // scan 640 bins: 3 bins/thread serial + Hillis-Steele over 256 thread sums
    int b0 = tid * 3;
    int c0 = (b0     < FINE_PER_B) ? cnt[b0]     : 0;
    int c1 = (b0 + 1 < FINE_PER_B) ? cnt[b0 + 1] : 0;
    int c2 = (b0 + 2 < FINE_PER_B) ? cnt[b0 + 2] : 0;
    int tsum = c0 + c1 + c2;
    tscan[tid] = tsum;
    __syncthreads();
    int acc = tsum;
    for (int off = 1; off < 256; off <<= 1) {
        int add = (tid >= off) ? tscan[tid - off] : 0;
        __syncthreads();
        acc += add;
        tscan[tid] = acc;
        __syncthreads();
    }
    int ex = acc - tsum;
    if (b0     < FINE_PER_B) scn[b0]     = ex;
    if (b0 + 1 < FINE_PER_B) scn[b0 + 1] = ex + c0;
    if (b0 + 2 < FINE_PER_B) scn[b0 + 2] = ex + c0 + c1;
    __syncthreads();
    for (int i = tid; i < n; i += 256) {
        uint2 r = recs[rbase + i];
        unsigned f = r.x >> 18;
        int p = scn[f] + atomicAdd(&cnt2[f], 1);
        srt[p] = make_uint2(r.x & 0x3FFFFu, r.y);   // strip tag: col only
    }
    __syncthreads();
    for (int i = tid; i < n; i += 256) sorted[rbase + i] = srt[i];
    for (int i = tid; i < FINE_PER_B; i += 256) {
        fineStart[cb * FINE_PER_B + i] = rbase + scn[i];
        fineCnt[cb * FINE_PER_B + i]   = cnt[i];
    }
}

// One wave per exact (slot, rel) run: single accumulator, zero tag logic,
// 2-deep MLP on the record->embedding chase. 164K short waves (R0-style TLP).
__global__ __launch_bounds__(256) void gather_fine(const uint2* __restrict__ sorted,
                                                   const float* __restrict__ uemb,
                                                   const float* __restrict__ iemb,
                                                   const int* __restrict__ fineStart,
                                                   const int* __restrict__ fineCnt,
                                                   const int* __restrict__ cnt,
                                                   unsigned short* __restrict__ agg) {
    int wid = (blockIdx.x * 256 + threadIdx.x) >> 6;
    int lane = threadIdx.x & 63;
    if (wid >= NFINE) return;
    int cb = wid / FINE_PER_B;
    int f = wid - cb * FINE_PER_B;
    int sl = f / N_REL;
    int rel = f - sl * N_REL;
    int slot = cb * 128 + sl;
    if (slot >= *cnt) return;

    int st = fineStart[wid];
    int hi = st + fineCnt[wid];
    float a = 0.0f;
    int e = st;
    for (; e + 2 <= hi; e += 2) {
        uint2 r0 = sorted[e], r1 = sorted[e + 1];
        const float* p0 = (r0.x < N_USERS) ? uemb + (size_t)r0.x * D : iemb + (size_t)(r0.x - N_USERS) * D;
        const float* p1 = (r1.x < N_USERS) ? uemb + (size_t)r1.x * D : iemb + (size_t)(r1.x - N_USERS) * D;
        a = fmaf(__uint_as_float(r0.y), p0[lane], a);
        a = fmaf(__uint_as_float(r1.y), p1[lane], a);
    }
    if (e < hi) {
        uint2 r = sorted[e];
        const float* p = (r.x < N_USERS) ? uemb + (size_t)r.x * D : iemb + (size_t)(r.x - N_USERS) * D;
        a = fmaf(__uint_as_float(r.y), p[lane], a);
    }
    agg[(size_t)slot * 320 + (size_t)rel * 64 + lane] = f2bf(a);
}

// LDS-tiled fused dense: 32 slots/block, 256 threads, 2x4 register tile/thread.
__global__ __launch_bounds__(256) void dense_tile(const unsigned short* __restrict__ agg,
                                                  const float* __restrict__ Wrel,
                                                  const float* __restrict__ brel,
                                                  const float* __restrict__ affW,
                                                  const float* __restrict__ affb,
                                                  const int* __restrict__ cnt,
                                                  float* __restrict__ logits) {
    __shared__ __align__(16) unsigned short shA[32][328];
    __shared__ __align__(16) unsigned short shM1[32][328];
    __shared__ __align__(16) float shW[64][68];

    int tid = threadIdx.x;
    int ty = tid >> 4, tx = tid & 15;
    int s0 = ty * 2;
    int j0 = tx * 4;
    int cval = *cnt;

    for (int tile = blockIdx.x; tile * 32 < cval; tile += gridDim.x) {
        __syncthreads();
        {
            const uint4* src = (const uint4*)(agg + (size_t)tile * 32 * 320);
            #pragma unroll
            for (int i = 0; i < 5; i++) {
                int idx = tid + i * 256;
                int p = idx * 8;
                int row = p / 320, col = p % 320;
                *(uint4*)&shA[row][col] = src[idx];
            }
        }
        #pragma unroll
        for (int k = 0; k < N_REL; k++) {
            __syncthreads();
            const float4* wsrc = (const float4*)(Wrel + (size_t)k * 4096);
            #pragma unroll
            for (int i = 0; i < 4; i++) {
                int idx = tid + i * 256;
                *(float4*)&shW[idx >> 4][(idx & 15) * 4] = wsrc[idx];
            }
            __syncthreads();
            float acc[2][4];
            #pragma unroll
            for (int jj = 0; jj < 4; jj++) {
                float b = brel[k * 64 + j0 + jj];
                acc[0][jj] = b; acc[1][jj] = b;
            }
            for (int d = 0; d < 64; d += 2) {
                unsigned pa0 = *(const unsigned*)&shA[s0][k * 64 + d];
                unsigned pa1 = *(const unsigned*)&shA[s0 + 1][k * 64 + d];
                float4 w0 = *(const float4*)&shW[d][j0];
                float4 w1 = *(const float4*)&shW[d + 1][j0];
                float a00 = bflo(pa0), a01 = bfhi(pa0);
                float a10 = bflo(pa1), a11 = bfhi(pa1);
                acc[0][0] = fmaf(a00, w0.x, fmaf(a01, w1.x, acc[0][0]));
                acc[0][1] = fmaf(a00, w0.y, fmaf(a01, w1.y, acc[0][1]));
                acc[0][2] = fmaf(a00, w0.z, fmaf(a01, w1.z, acc[0][2]));
                acc[0][3] = fmaf(a00, w0.w, fmaf(a01, w1.w, acc[0][3]));
                acc[1][0] = fmaf(a10, w0.x, fmaf(a11, w1.x, acc[1][0]));
                acc[1][1] = fmaf(a10, w0.y, fmaf(a11, w1.y, acc[1][1]));
                acc[1][2] = fmaf(a10, w0.z, fmaf(a11, w1.z, acc[1][2]));
                acc[1][3] = fmaf(a10, w0.w, fmaf(a11, w1.w, acc[1][3]));
            }
            #pragma unroll
            for (int i = 0; i < 2; i++) {
                #pragma unroll
                for (int jj = 0; jj < 4; jj++) {
                    float v = acc[i][jj];
                    acc[i][jj] = (v > 0.0f) ? v : 0.2f * v;   // leaky_relu 0.2
                }
                unsigned lo = (unsigned)f2bf(acc[i][0]) | ((unsigned)f2bf(acc[i][1]) << 16);
                unsigned hi = (unsigned)f2bf(acc[i][2]) | ((unsigned)f2bf(acc[i][3]) << 16);
                *(uint2*)&shM1[s0 + i][k * 64 + j0] = make_uint2(lo, hi);
            }
        }
        float acc2[2][4] = {{0,0,0,0},{0,0,0,0}};
        #pragma unroll
        for (int c = 0; c < N_REL; c++) {
            __syncthreads();
            const float4* wsrc = (const float4*)(affW + (size_t)c * 4096);
            #pragma unroll
            for (int i = 0; i < 4; i++) {
                int idx = tid + i * 256;
                *(float4*)&shW[idx >> 4][(idx & 15) * 4] = wsrc[idx];
            }
            __syncthreads();
            for (int dd = 0; dd < 64; dd += 2) {
                unsigned m0 = *(const unsigned*)&shM1[s0][c * 64 + dd];
                unsigned m1 = *(const unsigned*)&shM1[s0 + 1][c * 64 + dd];
                float4 w0 = *(const float4*)&shW[dd][j0];
                float4 w1 = *(const float4*)&shW[dd + 1][j0];
                float a00 = bflo(m0), a01 = bfhi(m0);
                float a10 = bflo(m1), a11 = bfhi(m1);
                acc2[0][0] = fmaf(a00, w0.x, fmaf(a01, w1.x, acc2[0][0]));
                acc2[0][1] = fmaf(a00, w0.y, fmaf(a01, w1.y, acc2[0][1]));
                acc2[0][2] = fmaf(a00, w0.z, fmaf(a01, w1.z, acc2[0][2]));
                acc2[0][3] = fmaf(a00, w0.w, fmaf(a01, w1.w, acc2[0][3]));
                acc2[1][0] = fmaf(a10, w0.x, fmaf(a11, w1.x, acc2[1][0]));
                acc2[1][1] = fmaf(a10, w0.y, fmaf(a11, w1.y, acc2[1][1]));
                acc2[1][2] = fmaf(a10, w0.z, fmaf(a11, w1.z, acc2[1][2]));
                acc2[1][3] = fmaf(a10, w0.w, fmaf(a11, w1.w, acc2[1][3]));
            }
        }
        float4 ab = *(const float4*)&affb[j0];
        #pragma unroll
        for (int i = 0; i < 2; i++) {
            float4 r;
            r.x = acc2[i][0] + ab.x; r.y = acc2[i][1] + ab.y;
            r.z = acc2[i][2] + ab.z; r.w = acc2[i][3] + ab.w;
            *(float4*)&logits[(size_t)(tile * 32 + s0 + i) * 64 + j0] = r;
        }
    }
}

__global__ __launch_bounds__(256) void finalize(const int* __restrict__ users,
                                                const int* __restrict__ items,
                                                const int* __restrict__ map,
                                                const float* __restrict__ logits,
                                                float* __restrict__ out) {
    int wave = (blockIdx.x * 256 + threadIdx.x) >> 6;
    int lane = threadIdx.x & 63;
    if (wave >= B_EVAL) return;
    int cu = map[users[wave]];
    int ci = map[N_USERS + items[wave]];
    float p = logits[(size_t)cu * D + lane] * logits[(size_t)ci * D + lane];
    #pragma unroll
    for (int off = 32; off > 0; off >>= 1) p += __shfl_down(p, off);
    if (lane == 0) out[wave] = p;
}

extern "C" void kernel_launch(void* const* d_in, const int* in_sizes, int n_in,
                              void* d_out, int out_size, void* d_ws, size_t ws_size,
                              hipStream_t stream) {
    const int*   users = (const int*)d_in[0];
    const int*   items = (const int*)d_in[1];
    const int*   rows  = (const int*)d_in[2];
    const int*   cols  = (const int*)d_in[3];
    const float* vals  = (const float*)d_in[4];
    const float* uemb  = (const float*)d_in[5];
    const float* iemb  = (const float*)d_in[6];
    const float* Wrel  = (const float*)d_in[7];
    const float* brel  = (const float*)d_in[8];
    const float* affW  = (const float*)d_in[9];
    const float* affb  = (const float*)d_in[10];
    float* out = (float*)d_out;

    char* ws = (char*)d_ws;
    int*   map     = (int*)(ws + OFF_MAP);
    int*   cnt     = (int*)(ws + OFF_CNT);
    int*   cursors = (int*)(ws + OFF_CUR);
    int*   fineSt  = (int*)(ws + OFF_FST);
    int*   fineCn  = (int*)(ws + OFF_FCN);
    uint2* recs    = (uint2*)(ws + OFF_RECS);
    uint2* sorted  = (uint2*)(ws + OFF_SORT);
    unsigned short* agg = (unsigned short*)(ws + OFF_AGG);
    float* logits  = (float*)(ws + OFF_LOG);

    (void)hipMemsetAsync(map, 0xFF, (size_t)N_NODES * sizeof(int), stream);  // map = -1
    (void)hipMemsetAsync(cnt, 0, sizeof(int), stream);

    build_map<<<(2 * B_EVAL + 255) / 256, 256, 0, stream>>>(users, items, map, cnt);
    init_cursors<<<1, 256, 0, stream>>>(cursors);
    fill_coarse<<<FILL_BLOCKS, 256, 0, stream>>>(rows, cols, vals, map, cursors, recs);
    sort_bucket<<<NCB, 256, 0, stream>>>(recs, cursors, sorted, fineSt, fineCn);
    gather_fine<<<(NFINE * 64) / 256, 256, 0, stream>>>(sorted, uemb, iemb, fineSt, fineCn, cnt, agg);
    dense_tile<<<1024, 256, 0, stream>>>(agg, Wrel, brel, affW, affb, cnt, logits);
    finalize<<<(B_EVAL * 64) / 256, 256, 0, stream>>>(users, items, map, logits, out);
}

// Round 13
// 456.723 us; speedup vs baseline: 2.4136x; 1.0867x over previous
//
#include <hip/hip_runtime.h>

#define N_USERS 100000
#define N_ITEMS 50000
#define N_NODES 150000
#define N_REL 5
#define NNZ 2000000
#define D 64
#define B_EVAL 16384
#define MAXSLOTS 32768
#define NCB 256                        /* coarse buckets: cb = slot>>7 */
#define BCAP 10240                     /* records per bucket region (avg 7578) */
#define FINE_PER_B 640                 /* 128 slots x 5 rels */
#define NFINE (NCB * FINE_PER_B)       /* 163840 fine bins */
#define EDGES_PER_BLOCK 2048
#define FILL_BLOCKS 4884               /* ceil(10M / 2048) */
#define TOTAL_EDGES (N_REL * NNZ)      /* 10,000,000 */

// -------- workspace layout (bytes) ----
// map:       int[150000]            @ 0
// cnt:       int                    @ 600,064
// cursors:   int[256]               @ 600,320
// fineStart: int[163840]            @ 601,344
// fineCnt:   int[163840]            @ 1,256,704
// recs:      uint2[256*10240]       @ 1,912,064   (21.0 MB)
// sorted:    uint2[256*10240]       @ 22,883,584  (21.0 MB)
// agg:       bf16[32768*320]        @ 1,912,064   (overlay recs - dead after sort)
// logits:    f32[32768*64]          @ 22,883,584  (overlay sorted - dead after gather)
// total footprint: 43,855,104 B
#define OFF_MAP   0
#define OFF_CNT   600064
#define OFF_CUR   600320
#define OFF_FST   601344
#define OFF_FCN   1256704
#define OFF_RECS  1912064
#define OFF_SORT  22883584
#define OFF_AGG   1912064
#define OFF_LOG   22883584

__device__ __forceinline__ unsigned short f2bf(float f) {   // RNE f32->bf16
    unsigned u = __float_as_uint(f);
    return (unsigned short)((u + 0x7FFFu + ((u >> 16) & 1u)) >> 16);
}
__device__ __forceinline__ float bflo(unsigned p) { return __uint_as_float(p << 16); }
__device__ __forceinline__ float bfhi(unsigned p) { return __uint_as_float(p & 0xFFFF0000u); }

__global__ __launch_bounds__(256) void build_map(const int* __restrict__ users,
                                                 const int* __restrict__ items,
                                                 int* __restrict__ map,
                                                 int* __restrict__ cnt) {
    int t = blockIdx.x * 256 + threadIdx.x;
    if (t >= 2 * B_EVAL) return;
    int node = (t < B_EVAL) ? users[t] : (N_USERS + items[t - B_EVAL]);
    if (atomicCAS(&map[node], -1, -2) == -1) {
        int idx = atomicAdd(cnt, 1);
        map[node] = idx;
    }
}

__global__ __launch_bounds__(256) void init_cursors(int* __restrict__ cursors) {
    cursors[threadIdx.x] = threadIdx.x * BCAP;   // fixed bucket regions -> no scan needed
}

// Each block owns 2K contiguous edges (4884 blocks: smooth drain, 8-iter
// serial chains). Full blocks take a compile-time-unrolled path: 8 map loads
// issue back-to-back (8-deep MLP). Pass 1 LDS-counts 256 coarse buckets and
// caches ci; one global atomicAdd per (block,bucket) reserves a contiguous
// chunk; pass 2 writes records contiguously from the LDS ci-cache.
// Tag: col (18b) | fine (10b @18), fine = (slot&127)*5 + rel.
__global__ __launch_bounds__(256) void fill_coarse(const int* __restrict__ rows,
                                                   const int* __restrict__ cols,
                                                   const float* __restrict__ vals,
                                                   const int* __restrict__ map,
                                                   int* __restrict__ cursors,
                                                   uint2* __restrict__ recs) {
    __shared__ int cnt1[NCB], cnt2[NCB], base[NCB];
    __shared__ short ciCache[EDGES_PER_BLOCK];   // 4 KB; ci in [-1, 32767]
    int tid = threadIdx.x;
    int e0 = blockIdx.x * EDGES_PER_BLOCK;
    int nE = TOTAL_EDGES - e0;
    if (nE <= 0) return;
    if (nE > EDGES_PER_BLOCK) nE = EDGES_PER_BLOCK;
    cnt1[tid] = 0; cnt2[tid] = 0;
    __syncthreads();

    if (nE == EDGES_PER_BLOCK) {
        // ---- full-block fast path: compile-time trip counts ----
        int ci_r[EDGES_PER_BLOCK / 256];
        #pragma unroll
        for (int j = 0; j < EDGES_PER_BLOCK / 256; j++)
            ci_r[j] = map[rows[e0 + tid + j * 256]];     // 8 independent loads in flight
        #pragma unroll
        for (int j = 0; j < EDGES_PER_BLOCK / 256; j++) {
            int ci = ci_r[j];
            ciCache[tid + j * 256] = (short)ci;
            if (ci >= 0) atomicAdd(&cnt1[ci >> 7], 1);
        }
        __syncthreads();
        if (cnt1[tid] > 0) base[tid] = atomicAdd(&cursors[tid], cnt1[tid]);
        __syncthreads();
        #pragma unroll
        for (int j = 0; j < EDGES_PER_BLOCK / 256; j++) {
            int i = tid + j * 256;
            int ci = ciCache[i];
            if (ci < 0) continue;
            int gid = e0 + i;
            int cb = ci >> 7;
            int r = atomicAdd(&cnt2[cb], 1);
            int pos = base[cb] + r;
            if (pos < (cb + 1) * BCAP) {
                int rel = gid / NNZ;
                unsigned fine = (unsigned)((ci & 127) * N_REL + rel);
                recs[pos] = make_uint2((unsigned)cols[gid] | (fine << 18), __float_as_uint(vals[gid]));
            }
        }
    } else {
        // ---- tail block (1 of 4884) ----
        for (int i = tid; i < nE; i += 256) {
            int ci = map[rows[e0 + i]];
            ciCache[i] = (short)ci;
            if (ci >= 0) atomicAdd(&cnt1[ci >> 7], 1);
        }
        __syncthreads();
        if (cnt1[tid] > 0) base[tid] = atomicAdd(&cursors[tid], cnt1[tid]);
        __syncthreads();
        for (int i = tid; i < nE; i += 256) {
            int ci = ciCache[i];
            if (ci < 0) continue;
            int gid = e0 + i;
            int cb = ci >> 7;
            int r = atomicAdd(&cnt2[cb], 1);
            int pos = base[cb] + r;
            if (pos < (cb + 1) * BCAP) {
                int rel = gid / NNZ;
                unsigned fine = (unsigned)((ci & 127) * N_REL + rel);
                recs[pos] = make_uint2((unsigned)cols[gid] | (fine << 18), __float_as_uint(vals[gid]));
            }
        }
    }
}

// One block per coarse bucket: count 640 fine bins in LDS, LDS scan, place all
// records at sorted positions in LDS (80KB), stream out coalesced full lines.
__global__ __launch_bounds__(256) void sort_bucket(const uint2* __restrict__ recs,
                                                   const int* __restrict__ cursors,
                                                   uint2* __restrict__ sorted,
                                                   int* __restrict__ fineStart,
                                                   int* __restrict__ fineCnt) {
    __shared__ int cnt[FINE_PER_B], scn[FINE_PER_B], cnt2[FINE_PER_B];
    __shared__ int tscan[256];
    __shared__ uint2 srt[BCAP];
    int cb = blockIdx.x, tid = threadIdx.x;
    int rbase = cb * BCAP;
    int n = cursors[cb] - rbase;
    if (n > BCAP) n = BCAP;
    for (int i = tid; i < FINE_PER_B; i += 256) { cnt[i] = 0; cnt2[i] = 0; }
    __syncthreads();
    for (int i = tid; i < n; i += 256) atomicAdd(&cnt[recs[rbase + i].x >> 18], 1);
    __syncthreads();
    // scan 640 bins: 3 bins/thread serial + Hillis-Steele over 256 thread sums
    int b0 = tid * 3;
    int c0 = (b0     < FINE_PER_B) ? cnt[b0]     : 0;
    int c1 = (b0 + 1 < FINE_PER_B) ? cnt[b0 + 1] : 0;
    int c2 = (b0 + 2 < FINE_PER_B) ? cnt[b0 + 2] : 0;
    int tsum = c0 + c1 + c2;
    tscan[tid] = tsum;
    __syncthreads();
    int acc = tsum;
    for (int off = 1; off < 256; off <<= 1) {
        int add = (tid >= off) ? tscan[tid - off] : 0;
        __syncthreads();
        acc += add;
        tscan[tid] = acc;
        __syncthreads();
    }
    int ex = acc - tsum;
    if (b0     < FINE_PER_B) scn[b0]     = ex;
    if (b0 + 1 < FINE_PER_B) scn[b0 + 1] = ex + c0;
    if (b0 + 2 < FINE_PER_B) scn[b0 + 2] = ex + c0 + c1;
    __syncthreads();
    for (int i = tid; i < n; i += 256) {
        uint2 r = recs[rbase + i];
        unsigned f = r.x >> 18;
        int p = scn[f] + atomicAdd(&cnt2[f], 1);
        srt[p] = make_uint2(r.x & 0x3FFFFu, r.y);   // strip tag: col only
    }
    __syncthreads();
    for (int i = tid; i < n; i += 256) sorted[rbase + i] = srt[i];
    for (int i = tid; i < FINE_PER_B; i += 256) {
        fineStart[cb * FINE_PER_B + i] = rbase + scn[i];
        fineCnt[cb * FINE_PER_B + i]   = cnt[i];
    }
}

// One wave per exact (slot, rel) run: single accumulator, zero tag logic,
// 4-deep MLP on the record->embedding chase. 164K short waves.
__global__ __launch_bounds__(256) void gather_fine(const uint2* __restrict__ sorted,
                                                   const float* __restrict__ uemb,
                                                   const float* __restrict__ iemb,
                                                   const int* __restrict__ fineStart,
                                                   const int* __restrict__ fineCnt,
                                                   const int* __restrict__ cnt,
                                                   unsigned short* __restrict__ agg) {
    int wid = (blockIdx.x * 256 + threadIdx.x) >> 6;
    int lane = threadIdx.x & 63;
    if (wid >= NFINE) return;
    int cb = wid / FINE_PER_B;
    int f = wid - cb * FINE_PER_B;
    int sl = f / N_REL;
    int rel = f - sl * N_REL;
    int slot = cb * 128 + sl;
    if (slot >= *cnt) return;

    int st = fineStart[wid];
    int hi = st + fineCnt[wid];
    float a0 = 0.0f, a1 = 0.0f;
    int e = st;
    for (; e + 4 <= hi; e += 4) {
        uint2 r0 = sorted[e], r1 = sorted[e + 1], r2 = sorted[e + 2], r3 = sorted[e + 3];
        const float* p0 = (r0.x < N_USERS) ? uemb + (size_t)r0.x * D : iemb + (size_t)(r0.x - N_USERS) * D;
        const float* p1 = (r1.x < N_USERS) ? uemb + (size_t)r1.x * D : iemb + (size_t)(r1.x - N_USERS) * D;
        const float* p2 = (r2.x < N_USERS) ? uemb + (size_t)r2.x * D : iemb + (size_t)(r2.x - N_USERS) * D;
        const float* p3 = (r3.x < N_USERS) ? uemb + (size_t)r3.x * D : iemb + (size_t)(r3.x - N_USERS) * D;
        float e0 = p0[lane], e1 = p1[lane], e2 = p2[lane], e3 = p3[lane];
        a0 = fmaf(__uint_as_float(r0.y), e0, a0);
        a1 = fmaf(__uint_as_float(r1.y), e1, a1);
        a0 = fmaf(__uint_as_float(r2.y), e2, a0);
        a1 = fmaf(__uint_as_float(r3.y), e3, a1);
    }
    for (; e < hi; e++) {
        uint2 r = sorted[e];
        const float* p = (r.x < N_USERS) ? uemb + (size_t)r.x * D : iemb + (size_t)(r.x - N_USERS) * D;
        a0 = fmaf(__uint_as_float(r.y), p[lane], a0);
    }
    agg[(size_t)slot * 320 + (size_t)rel * 64 + lane] = f2bf(a0 + a1);
}

// LDS-tiled fused dense: 32 slots/block, 256 threads, 2x4 register tile/thread.
__global__ __launch_bounds__(256) void dense_tile(const unsigned short* __restrict__ agg,
                                                  const float* __restrict__ Wrel,
                                                  const float* __restrict__ brel,
                                                  const float* __restrict__ affW,
                                                  const float* __restrict__ affb,
                                                  const int* __restrict__ cnt,
                                                  float* __restrict__ logits) {
    __shared__ __align__(16) unsigned short shA[32][328];
    __shared__ __align__(16) unsigned short shM1[32][328];
    __shared__ __align__(16) float shW[64][68];

    int tid = threadIdx.x;
    int ty = tid >> 4, tx = tid & 15;
    int s0 = ty * 2;
    int j0 = tx * 4;
    int cval = *cnt;

    for (int tile = blockIdx.x; tile * 32 < cval; tile += gridDim.x) {
        __syncthreads();
        {
            const uint4* src = (const uint4*)(agg + (size_t)tile * 32 * 320);
            #pragma unroll
            for (int i = 0; i < 5; i++) {
                int idx = tid + i * 256;
                int p = idx * 8;
                int row = p / 320, col = p % 320;
                *(uint4*)&shA[row][col] = src[idx];
            }
        }
        #pragma unroll
        for (int k = 0; k < N_REL; k++) {
            __syncthreads();
            const float4* wsrc = (const float4*)(Wrel + (size_t)k * 4096);
            #pragma unroll
            for (int i = 0; i < 4; i++) {
                int idx = tid + i * 256;
                *(float4*)&shW[idx >> 4][(idx & 15) * 4] = wsrc[idx];
            }
            __syncthreads();
            float acc[2][4];
            #pragma unroll
            for (int jj = 0; jj < 4; jj++) {
                float b = brel[k * 64 + j0 + jj];
                acc[0][jj] = b; acc[1][jj] = b;
            }
            for (int d = 0; d < 64; d += 2) {
                unsigned pa0 = *(const unsigned*)&shA[s0][k * 64 + d];
                unsigned pa1 = *(const unsigned*)&shA[s0 + 1][k * 64 + d];
                float4 w0 = *(const float4*)&shW[d][j0];
                float4 w1 = *(const float4*)&shW[d + 1][j0];
                float a00 = bflo(pa0), a01 = bfhi(pa0);
                float a10 = bflo(pa1), a11 = bfhi(pa1);
                acc[0][0] = fmaf(a00, w0.x, fmaf(a01, w1.x, acc[0][0]));
                acc[0][1] = fmaf(a00, w0.y, fmaf(a01, w1.y, acc[0][1]));
                acc[0][2] = fmaf(a00, w0.z, fmaf(a01, w1.z, acc[0][2]));
                acc[0][3] = fmaf(a00, w0.w, fmaf(a01, w1.w, acc[0][3]));
                acc[1][0] = fmaf(a10, w0.x, fmaf(a11, w1.x, acc[1][0]));
                acc[1][1] = fmaf(a10, w0.y, fmaf(a11, w1.y, acc[1][1]));
                acc[1][2] = fmaf(a10, w0.z, fmaf(a11, w1.z, acc[1][2]));
                acc[1][3] = fmaf(a10, w0.w, fmaf(a11, w1.w, acc[1][3]));
            }
            #pragma unroll
            for (int i = 0; i < 2; i++) {
                #pragma unroll
                for (int jj = 0; jj < 4; jj++) {
                    float v = acc[i][jj];
                    acc[i][jj] = (v > 0.0f) ? v : 0.2f * v;   // leaky_relu 0.2
                }
                unsigned lo = (unsigned)f2bf(acc[i][0]) | ((unsigned)f2bf(acc[i][1]) << 16);
                unsigned hi = (unsigned)f2bf(acc[i][2]) | ((unsigned)f2bf(acc[i][3]) << 16);
                *(uint2*)&shM1[s0 + i][k * 64 + j0] = make_uint2(lo, hi);
            }
        }
        float acc2[2][4] = {{0,0,0,0},{0,0,0,0}};
        #pragma unroll
        for (int c = 0; c < N_REL; c++) {
            __syncthreads();
            const float4* wsrc = (const float4*)(affW + (size_t)c * 4096);
            #pragma unroll
            for (int i = 0; i < 4; i++) {
                int idx = tid + i * 256;
                *(float4*)&shW[idx >> 4][(idx & 15) * 4] = wsrc[idx];
            }
            __syncthreads();
            for (int dd = 0; dd < 64; dd += 2) {
                unsigned m0 = *(const unsigned*)&shM1[s0][c * 64 + dd];
                unsigned m1 = *(const unsigned*)&shM1[s0 + 1][c * 64 + dd];
                float4 w0 = *(const float4*)&shW[dd][j0];
                float4 w1 = *(const float4*)&shW[dd + 1][j0];
                float a00 = bflo(m0), a01 = bfhi(m0);
                float a10 = bflo(m1), a11 = bfhi(m1);
                acc2[0][0] = fmaf(a00, w0.x, fmaf(a01, w1.x, acc2[0][0]));
                acc2[0][1] = fmaf(a00, w0.y, fmaf(a01, w1.y, acc2[0][1]));
                acc2[0][2] = fmaf(a00, w0.z, fmaf(a01, w1.z, acc2[0][2]));
                acc2[0][3] = fmaf(a00, w0.w, fmaf(a01, w1.w, acc2[0][3]));
                acc2[1][0] = fmaf(a10, w0.x, fmaf(a11, w1.x, acc2[1][0]));
                acc2[1][1] = fmaf(a10, w0.y, fmaf(a11, w1.y, acc2[1][1]));
                acc2[1][2] = fmaf(a10, w0.z, fmaf(a11, w1.z, acc2[1][2]));
                acc2[1][3] = fmaf(a10, w0.w, fmaf(a11, w1.w, acc2[1][3]));
            }
        }
        float4 ab = *(const float4*)&affb[j0];
        #pragma unroll
        for (int i = 0; i < 2; i++) {
            float4 r;
            r.x = acc2[i][0] + ab.x; r.y = acc2[i][1] + ab.y;
            r.z = acc2[i][2] + ab.z; r.w = acc2[i][3] + ab.w;
            *(float4*)&logits[(size_t)(tile * 32 + s0 + i) * 64 + j0] = r;
        }
    }
}

__global__ __launch_bounds__(256) void finalize(const int* __restrict__ users,
                                                const int* __restrict__ items,
                                                const int* __restrict__ map,
                                                const float* __restrict__ logits,
                                                float* __restrict__ out) {
    int wave = (blockIdx.x * 256 + threadIdx.x) >> 6;
    int lane = threadIdx.x & 63;
    if (wave >= B_EVAL) return;
    int cu = map[users[wave]];
    int ci = map[N_USERS + items[wave]];
    float p = logits[(size_t)cu * D + lane] * logits[(size_t)ci * D + lane];
    #pragma unroll
    for (int off = 32; off > 0; off >>= 1) p += __shfl_down(p, off);
    if (lane == 0) out[wave] = p;
}

extern "C" void kernel_launch(void* const* d_in, const int* in_sizes, int n_in,
                              void* d_out, int out_size, void* d_ws, size_t ws_size,
                              hipStream_t stream) {
    const int*   users = (const int*)d_in[0];
    const int*   items = (const int*)d_in[1];
    const int*   rows  = (const int*)d_in[2];
    const int*   cols  = (const int*)d_in[3];
    const float* vals  = (const float*)d_in[4];
    const float* uemb  = (const float*)d_in[5];
    const float* iemb  = (const float*)d_in[6];
    const float* Wrel  = (const float*)d_in[7];
    const float* brel  = (const float*)d_in[8];
    const float* affW  = (const float*)d_in[9];
    const float* affb  = (const float*)d_in[10];
    float* out = (float*)d_out;

    char* ws = (char*)d_ws;
    int*   map     = (int*)(ws + OFF_MAP);
    int*   cnt     = (int*)(ws + OFF_CNT);
    int*   cursors = (int*)(ws + OFF_CUR);
    int*   fineSt  = (int*)(ws + OFF_FST);
    int*   fineCn  = (int*)(ws + OFF_FCN);
    uint2* recs    = (uint2*)(ws + OFF_RECS);
    uint2* sorted  = (uint2*)(ws + OFF_SORT);
    unsigned short* agg = (unsigned short*)(ws + OFF_AGG);
    float* logits  = (float*)(ws + OFF_LOG);

    (void)hipMemsetAsync(map, 0xFF, (size_t)N_NODES * sizeof(int), stream);  // map = -1
    (void)hipMemsetAsync(cnt, 0, sizeof(int), stream);

    build_map<<<(2 * B_EVAL + 255) / 256, 256, 0, stream>>>(users, items, map, cnt);
    init_cursors<<<1, 256, 0, stream>>>(cursors);
    fill_coarse<<<FILL_BLOCKS, 256, 0, stream>>>(rows, cols, vals, map, cursors, recs);
    sort_bucket<<<NCB, 256, 0, stream>>>(recs, cursors, sorted, fineSt, fineCn);
    gather_fine<<<(NFINE * 64) / 256, 256, 0, stream>>>(sorted, uemb, iemb, fineSt, fineCn, cnt, agg);
    dense_tile<<<1024, 256, 0, stream>>>(agg, Wrel, brel, affW, affb, cnt, logits);
    finalize<<<(B_EVAL * 64) / 256, 256, 0, stream>>>(users, items, map, logits, out);
}

// Round 14
// 434.414 us; speedup vs baseline: 2.5375x; 1.0514x over previous
//
#include <hip/hip_runtime.h>

#define N_USERS 100000
#define N_ITEMS 50000
#define N_NODES 150000
#define N_REL 5
#define NNZ 2000000
#define D 64
#define B_EVAL 16384
#define MAXSLOTS 32768
#define NCB 256                        /* coarse buckets: cb = slot>>7 */
#define NSTRIPE 8
#define SBCAP 1280                     /* records per (stripe,bucket) region */
#define BCAP (NSTRIPE * SBCAP)         /* 10240 per bucket total (R11-proven headroom) */
#define FINE_PER_B 640                 /* 128 slots x 5 rels */
#define NFINE (NCB * FINE_PER_B)       /* 163840 fine bins */
#define EDGES_PER_BLOCK 2048
#define FILL_BLOCKS 4884               /* ceil(10M / 2048) */
#define TOTAL_EDGES (N_REL * NNZ)      /* 10,000,000 */

// -------- workspace layout (bytes) ----
// map:       int[150000]            @ 0
// cnt:       int                    @ 600,064
// cursors:   int[2048]              @ 600,320    (8 KB: stripe-major, XCD-local)
// fineStart: int[163840]            @ 608,512
// fineCnt:   int[163840]            @ 1,263,872
// recs:      uint2[2,621,440]       @ 1,919,232  (21.0 MB; 2048 regions x 1280)
// sorted:    uint2[2,621,440]       @ 22,890,752 (21.0 MB)
// agg:       bf16[32768*320]        @ 1,919,232  (overlay recs - dead after sort)
// logits:    f32[32768*64]          @ 22,890,752 (overlay sorted - dead after gather)
// total footprint: 43,862,272 B
#define OFF_MAP   0
#define OFF_CNT   600064
#define OFF_CUR   600320
#define OFF_FST   608512
#define OFF_FCN   1263872
#define OFF_RECS  1919232
#define OFF_SORT  22890752
#define OFF_AGG   1919232
#define OFF_LOG   22890752

__device__ __forceinline__ unsigned short f2bf(float f) {   // RNE f32->bf16
    unsigned u = __float_as_uint(f);
    return (unsigned short)((u + 0x7FFFu + ((u >> 16) & 1u)) >> 16);
}
__device__ __forceinline__ float bflo(unsigned p) { return __uint_as_float(p << 16); }
__device__ __forceinline__ float bfhi(unsigned p) { return __uint_as_float(p & 0xFFFF0000u); }

__global__ __launch_bounds__(256) void build_map(const int* __restrict__ users,
                                                 const int* __restrict__ items,
                                                 int* __restrict__ map,
                                                 int* __restrict__ cnt) {
    int t = blockIdx.x * 256 + threadIdx.x;
    if (t >= 2 * B_EVAL) return;
    int node = (t < B_EVAL) ? users[t] : (N_USERS + items[t - B_EVAL]);
    if (atomicCAS(&map[node], -1, -2) == -1) {
        int idx = atomicAdd(cnt, 1);
        map[node] = idx;
    }
}

__global__ __launch_bounds__(256) void init_cursors(int* __restrict__ cursors) {
    #pragma unroll
    for (int j = 0; j < NSTRIPE; j++) {
        int i = j * 256 + threadIdx.x;
        cursors[i] = i * SBCAP;        // fixed (stripe,bucket) regions -> no scan
    }
}

// Each block owns 2K contiguous edges. Cursor array is striped by blockIdx&7:
// 8x fewer atomics per line, and stripe-s cursors are only touched by blocks
// on XCD s (round-robin dispatch) -> atomic line stays home-L2-resident
// instead of ping-ponging across 8 XCDs (R13's serialization suspect).
// Tag: col (18b) | fine (10b @18), fine = (slot&127)*5 + rel.
__global__ __launch_bounds__(256) void fill_coarse(const int* __restrict__ rows,
                                                   const int* __restrict__ cols,
                                                   const float* __restrict__ vals,
                                                   const int* __restrict__ map,
                                                   int* __restrict__ cursors,
                                                   uint2* __restrict__ recs) {
    __shared__ int cnt1[NCB], cnt2[NCB], base[NCB];
    __shared__ short ciCache[EDGES_PER_BLOCK];   // 4 KB; ci in [-1, 32767]
    int tid = threadIdx.x;
    int stripe = blockIdx.x & 7;
    int e0 = blockIdx.x * EDGES_PER_BLOCK;
    int nE = TOTAL_EDGES - e0;
    if (nE <= 0) return;
    if (nE > EDGES_PER_BLOCK) nE = EDGES_PER_BLOCK;
    cnt1[tid] = 0; cnt2[tid] = 0;
    __syncthreads();

    if (nE == EDGES_PER_BLOCK) {
        // ---- full-block fast path: compile-time trip counts, 8-deep MLP ----
        int ci_r[EDGES_PER_BLOCK / 256];
        #pragma unroll
        for (int j = 0; j < EDGES_PER_BLOCK / 256; j++)
            ci_r[j] = map[rows[e0 + tid + j * 256]];
        #pragma unroll
        for (int j = 0; j < EDGES_PER_BLOCK / 256; j++) {
            int ci = ci_r[j];
            ciCache[tid + j * 256] = (short)ci;
            if (ci >= 0) atomicAdd(&cnt1[ci >> 7], 1);
        }
        __syncthreads();
        if (cnt1[tid] > 0) base[tid] = atomicAdd(&cursors[stripe * NCB + tid], cnt1[tid]);
        __syncthreads();
        #pragma unroll
        for (int j = 0; j < EDGES_PER_BLOCK / 256; j++) {
            int i = tid + j * 256;
            int ci = ciCache[i];
            if (ci < 0) continue;
            int gid = e0 + i;
            int cb = ci >> 7;
            int r = atomicAdd(&cnt2[cb], 1);
            int pos = base[cb] + r;
            if (pos < (stripe * NCB + cb + 1) * SBCAP) {   // overflow guard
                int rel = gid / NNZ;
                unsigned fine = (unsigned)((ci & 127) * N_REL + rel);
                recs[pos] = make_uint2((unsigned)cols[gid] | (fine << 18), __float_as_uint(vals[gid]));
            }
        }
    } else {
        // ---- tail block (1 of 4884) ----
        for (int i = tid; i < nE; i += 256) {
            int ci = map[rows[e0 + i]];
            ciCache[i] = (short)ci;
            if (ci >= 0) atomicAdd(&cnt1[ci >> 7], 1);
        }
        __syncthreads();
        if (cnt1[tid] > 0) base[tid] = atomicAdd(&cursors[stripe * NCB + tid], cnt1[tid]);
        __syncthreads();
        for (int i = tid; i < nE; i += 256) {
            int ci = ciCache[i];
            if (ci < 0) continue;
            int gid = e0 + i;
            int cb = ci >> 7;
            int r = atomicAdd(&cnt2[cb], 1);
            int pos = base[cb] + r;
            if (pos < (stripe * NCB + cb + 1) * SBCAP) {
                int rel = gid / NNZ;
                unsigned fine = (unsigned)((ci & 127) * N_REL + rel);
                recs[pos] = make_uint2((unsigned)cols[gid] | (fine << 18), __float_as_uint(vals[gid]));
            }
        }
    }
}

// One block per coarse bucket: read the bucket's 8 stripe-runs, count 640 fine
// bins in LDS, LDS scan, place records at sorted positions in LDS (80KB),
// stream out coalesced full lines. Emits fineStart/fineCnt for the gather.
__global__ __launch_bounds__(256) void sort_bucket(const uint2* __restrict__ recs,
                                                   const int* __restrict__ cursors,
                                                   uint2* __restrict__ sorted,
                                                   int* __restrict__ fineStart,
                                                   int* __restrict__ fineCnt) {
    __shared__ int cnt[FINE_PER_B], scn[FINE_PER_B], cnt2[FINE_PER_B];
    __shared__ int tscan[256];
    __shared__ uint2 srt[BCAP];
    int cb = blockIdx.x, tid = threadIdx.x;

    int ns[NSTRIPE], rb[NSTRIPE];
    #pragma unroll
    for (int s = 0; s < NSTRIPE; s++) {
        int seg = s * NCB + cb;
        rb[s] = seg * SBCAP;
        int n = cursors[seg] - rb[s];
        ns[s] = (n > SBCAP) ? SBCAP : n;
    }

    for (int i = tid; i < FINE_PER_B; i += 256) { cnt[i] = 0; cnt2[i] = 0; }
    __syncthreads();
    #pragma unroll
    for (int s = 0; s < NSTRIPE; s++)
        for (int i = tid; i < ns[s]; i += 256)
            atomicAdd(&cnt[recs[rb[s] + i].x >> 18], 1);
    __syncthreads();
    // scan 640 bins: 3 bins/thread serial + Hillis-Steele over 256 thread sums
    int b0 = tid * 3;
    int c0 = (b0     < FINE_PER_B) ? cnt[b0]     : 0;
    int c1 = (b0 + 1 < FINE_PER_B) ? cnt[b0 + 1] : 0;
    int c2 = (b0 + 2 < FINE_PER_B) ? cnt[b0 + 2] : 0;
    int tsum = c0 + c1 + c2;
    tscan[tid] = tsum;
    __syncthreads();
    int acc = tsum;
    for (int off = 1; off < 256; off <<= 1) {
        int add = (tid >= off) ? tscan[tid - off] : 0;
        __syncthreads();
        acc += add;
        tscan[tid] = acc;
        __syncthreads();
    }
    int ex = acc - tsum;
    if (b0     < FINE_PER_B) scn[b0]     = ex;
    if (b0 + 1 < FINE_PER_B) scn[b0 + 1] = ex + c0;
    if (b0 + 2 < FINE_PER_B) scn[b0 + 2] = ex + c0 + c1;
    __syncthreads();
    #pragma unroll
    for (int s = 0; s < NSTRIPE; s++)
        for (int i = tid; i < ns[s]; i += 256) {
            uint2 r = recs[rb[s] + i];
            unsigned f = r.x >> 18;
            int p = scn[f] + atomicAdd(&cnt2[f], 1);
            srt[p] = make_uint2(r.x & 0x3FFFFu, r.y);   // strip tag: col only
        }
    __syncthreads();
    int total = 0;
    #pragma unroll
    for (int s = 0; s < NSTRIPE; s++) total += ns[s];
    int obase = cb * BCAP;
    for (int i = tid; i < total; i += 256) sorted[obase + i] = srt[i];
    for (int i = tid; i < FINE_PER_B; i += 256) {
        fineStart[cb * FINE_PER_B + i] = obase + scn[i];
        fineCnt[cb * FINE_PER_B + i]   = cnt[i];
    }
}

// One wave per exact (slot, rel) run: single accumulator, zero tag logic,
// 4-deep MLP on the record->embedding chase. 164K short waves.
__global__ __launch_bounds__(256) void gather_fine(const uint2* __restrict__ sorted,
                                                   const float* __restrict__ uemb,
                                                   const float* __restrict__ iemb,
                                                   const int* __restrict__ fineStart,
                                                   const int* __restrict__ fineCnt,
                                                   const int* __restrict__ cnt,
                                                   unsigned short* __restrict__ agg) {
    int wid = (blockIdx.x * 256 + threadIdx.x) >> 6;
    int lane = threadIdx.x & 63;
    if (wid >= NFINE) return;
    int cb = wid / FINE_PER_B;
    int f = wid - cb * FINE_PER_B;
    int sl = f / N_REL;
    int rel = f - sl * N_REL;
    int slot = cb * 128 + sl;
    if (slot >= *cnt) return;

    int st = fineStart[wid];
    int hi = st + fineCnt[wid];
    float a0 = 0.0f, a1 = 0.0f;
    int e = st;
    for (; e + 4 <= hi; e += 4) {
        uint2 r0 = sorted[e], r1 = sorted[e + 1], r2 = sorted[e + 2], r3 = sorted[e + 3];
        const float* p0 = (r0.x < N_USERS) ? uemb + (size_t)r0.x * D : iemb + (size_t)(r0.x - N_USERS) * D;
        const float* p1 = (r1.x < N_USERS) ? uemb + (size_t)r1.x * D : iemb + (size_t)(r1.x - N_USERS) * D;
        const float* p2 = (r2.x < N_USERS) ? uemb + (size_t)r2.x * D : iemb + (size_t)(r2.x - N_USERS) * D;
        const float* p3 = (r3.x < N_USERS) ? uemb + (size_t)r3.x * D : iemb + (size_t)(r3.x - N_USERS) * D;
        float e0 = p0[lane], e1 = p1[lane], e2 = p2[lane], e3 = p3[lane];
        a0 = fmaf(__uint_as_float(r0.y), e0, a0);
        a1 = fmaf(__uint_as_float(r1.y), e1, a1);
        a0 = fmaf(__uint_as_float(r2.y), e2, a0);
        a1 = fmaf(__uint_as_float(r3.y), e3, a1);
    }
    for (; e < hi; e++) {
        uint2 r = sorted[e];
        const float* p = (r.x < N_USERS) ? uemb + (size_t)r.x * D : iemb + (size_t)(r.x - N_USERS) * D;
        a0 = fmaf(__uint_as_float(r.y), p[lane], a0);
    }
    agg[(size_t)slot * 320 + (size_t)rel * 64 + lane] = f2bf(a0 + a1);
}

// LDS-tiled fused dense: 32 slots/block, 256 threads, 2x4 register tile/thread.
__global__ __launch_bounds__(256) void dense_tile(const unsigned short* __restrict__ agg,
                                                  const float* __restrict__ Wrel,
                                                  const float* __restrict__ brel,
                                                  const float* __restrict__ affW,
                                                  const float* __restrict__ affb,
                                                  const int* __restrict__ cnt,
                                                  float* __restrict__ logits) {
    __shared__ __align__(16) unsigned short shA[32][328];
    __shared__ __align__(16) unsigned short shM1[32][328];
    __shared__ __align__(16) float shW[64][68];

    int tid = threadIdx.x;
    int ty = tid >> 4, tx = tid & 15;
    int s0 = ty * 2;
    int j0 = tx * 4;
    int cval = *cnt;

    for (int tile = blockIdx.x; tile * 32 < cval; tile += gridDim.x) {
        __syncthreads();
        {
            const uint4* src = (const uint4*)(agg + (size_t)tile * 32 * 320);
            #pragma unroll
            for (int i = 0; i < 5; i++) {
                int idx = tid + i * 256;
                int p = idx * 8;
                int row = p / 320, col = p % 320;
                *(uint4*)&shA[row][col] = src[idx];
            }
        }
        #pragma unroll
        for (int k = 0; k < N_REL; k++) {
            __syncthreads();
            const float4* wsrc = (const float4*)(Wrel + (size_t)k * 4096);
            #pragma unroll
            for (int i = 0; i < 4; i++) {
                int idx = tid + i * 256;
                *(float4*)&shW[idx >> 4][(idx & 15) * 4] = wsrc[idx];
            }
            __syncthreads();
            float acc[2][4];
            #pragma unroll
            for (int jj = 0; jj < 4; jj++) {
                float b = brel[k * 64 + j0 + jj];
                acc[0][jj] = b; acc[1][jj] = b;
            }
            for (int d = 0; d < 64; d += 2) {
                unsigned pa0 = *(const unsigned*)&shA[s0][k * 64 + d];
                unsigned pa1 = *(const unsigned*)&shA[s0 + 1][k * 64 + d];
                float4 w0 = *(const float4*)&shW[d][j0];
                float4 w1 = *(const float4*)&shW[d + 1][j0];
                float a00 = bflo(pa0), a01 = bfhi(pa0);
                float a10 = bflo(pa1), a11 = bfhi(pa1);
                acc[0][0] = fmaf(a00, w0.x, fmaf(a01, w1.x, acc[0][0]));
                acc[0][1] = fmaf(a00, w0.y, fmaf(a01, w1.y, acc[0][1]));
                acc[0][2] = fmaf(a00, w0.z, fmaf(a01, w1.z, acc[0][2]));
                acc[0][3] = fmaf(a00, w0.w, fmaf(a01, w1.w, acc[0][3]));
                acc[1][0] = fmaf(a10, w0.x, fmaf(a11, w1.x, acc[1][0]));
                acc[1][1] = fmaf(a10, w0.y, fmaf(a11, w1.y, acc[1][1]));
                acc[1][2] = fmaf(a10, w0.z, fmaf(a11, w1.z, acc[1][2]));
                acc[1][3] = fmaf(a10, w0.w, fmaf(a11, w1.w, acc[1][3]));
            }
            #pragma unroll
            for (int i = 0; i < 2; i++) {
                #pragma unroll
                for (int jj = 0; jj < 4; jj++) {
                    float v = acc[i][jj];
                    acc[i][jj] = (v > 0.0f) ? v : 0.2f * v;   // leaky_relu 0.2
                }
                unsigned lo = (unsigned)f2bf(acc[i][0]) | ((unsigned)f2bf(acc[i][1]) << 16);
                unsigned hi = (unsigned)f2bf(acc[i][2]) | ((unsigned)f2bf(acc[i][3]) << 16);
                *(uint2*)&shM1[s0 + i][k * 64 + j0] = make_uint2(lo, hi);
            }
        }
        float acc2[2][4] = {{0,0,0,0},{0,0,0,0}};
        #pragma unroll
        for (int c = 0; c < N_REL; c++) {
            __syncthreads();
            const float4* wsrc = (const float4*)(affW + (size_t)c * 4096);
            #pragma unroll
            for (int i = 0; i < 4; i++) {
                int idx = tid + i * 256;
                *(float4*)&shW[idx >> 4][(idx & 15) * 4] = wsrc[idx];
            }
            __syncthreads();
            for (int dd = 0; dd < 64; dd += 2) {
                unsigned m0 = *(const unsigned*)&shM1[s0][c * 64 + dd];
                unsigned m1 = *(const unsigned*)&shM1[s0 + 1][c * 64 + dd];
                float4 w0 = *(const float4*)&shW[dd][j0];
                float4 w1 = *(const float4*)&shW[dd + 1][j0];
                float a00 = bflo(m0), a01 = bfhi(m0);
                float a10 = bflo(m1), a11 = bfhi(m1);
                acc2[0][0] = fmaf(a00, w0.x, fmaf(a01, w1.x, acc2[0][0]));
                acc2[0][1] = fmaf(a00, w0.y, fmaf(a01, w1.y, acc2[0][1]));
                acc2[0][2] = fmaf(a00, w0.z, fmaf(a01, w1.z, acc2[0][2]));
                acc2[0][3] = fmaf(a00, w0.w, fmaf(a01, w1.w, acc2[0][3]));
                acc2[1][0] = fmaf(a10, w0.x, fmaf(a11, w1.x, acc2[1][0]));
                acc2[1][1] = fmaf(a10, w0.y, fmaf(a11, w1.y, acc2[1][1]));
                acc2[1][2] = fmaf(a10, w0.z, fmaf(a11, w1.z, acc2[1][2]));
                acc2[1][3] = fmaf(a10, w0.w, fmaf(a11, w1.w, acc2[1][3]));
            }
        }
        float4 ab = *(const float4*)&affb[j0];
        #pragma unroll
        for (int i = 0; i < 2; i++) {
            float4 r;
            r.x = acc2[i][0] + ab.x; r.y = acc2[i][1] + ab.y;
            r.z = acc2[i][2] + ab.z; r.w = acc2[i][3] + ab.w;
            *(float4*)&logits[(size_t)(tile * 32 + s0 + i) * 64 + j0] = r;
        }
    }
}

__global__ __launch_bounds__(256) void finalize(const int* __restrict__ users,
                                                const int* __restrict__ items,
                                                const int* __restrict__ map,
                                                const float* __restrict__ logits,
                                                float* __restrict__ out) {
    int wave = (blockIdx.x * 256 + threadIdx.x) >> 6;
    int lane = threadIdx.x & 63;
    if (wave >= B_EVAL) return;
    int cu = map[users[wave]];
    int ci = map[N_USERS + items[wave]];
    float p = logits[(size_t)cu * D + lane] * logits[(size_t)ci * D + lane];
    #pragma unroll
    for (int off = 32; off > 0; off >>= 1) p += __shfl_down(p, off);
    if (lane == 0) out[wave] = p;
}

extern "C" void kernel_launch(void* const* d_in, const int* in_sizes, int n_in,
                              void* d_out, int out_size, void* d_ws, size_t ws_size,
                              hipStream_t stream) {
    const int*   users = (const int*)d_in[0];
    const int*   items = (const int*)d_in[1];
    const int*   rows  = (const int*)d_in[2];
    const int*   cols  = (const int*)d_in[3];
    const float* vals  = (const float*)d_in[4];
    const float* uemb  = (const float*)d_in[5];
    const float* iemb  = (const float*)d_in[6];
    const float* Wrel  = (const float*)d_in[7];
    const float* brel  = (const float*)d_in[8];
    const float* affW  = (const float*)d_in[9];
    const float* affb  = (const float*)d_in[10];
    float* out = (float*)d_out;

    char* ws = (char*)d_ws;
    int*   map     = (int*)(ws + OFF_MAP);
    int*   cnt     = (int*)(ws + OFF_CNT);
    int*   cursors = (int*)(ws + OFF_CUR);
    int*   fineSt  = (int*)(ws + OFF_FST);
    int*   fineCn  = (int*)(ws + OFF_FCN);
    uint2* recs    = (uint2*)(ws + OFF_RECS);
    uint2* sorted  = (uint2*)(ws + OFF_SORT);
    unsigned short* agg = (unsigned short*)(ws + OFF_AGG);
    float* logits  = (float*)(ws + OFF_LOG);

    (void)hipMemsetAsync(map, 0xFF, (size_t)N_NODES * sizeof(int), stream);  // map = -1
    (void)hipMemsetAsync(cnt, 0, sizeof(int), stream);

    build_map<<<(2 * B_EVAL + 255) / 256, 256, 0, stream>>>(users, items, map, cnt);
    init_cursors<<<1, 256, 0, stream>>>(cursors);
    fill_coarse<<<FILL_BLOCKS, 256, 0, stream>>>(rows, cols, vals, map, cursors, recs);
    sort_bucket<<<NCB, 256, 0, stream>>>(recs, cursors, sorted, fineSt, fineCn);
    gather_fine<<<(NFINE * 64) / 256, 256, 0, stream>>>(sorted, uemb, iemb, fineSt, fineCn, cnt, agg);
    dense_tile<<<1024, 256, 0, stream>>>(agg, Wrel, brel, affW, affb, cnt, logits);
    finalize<<<(B_EVAL * 64) / 256, 256, 0, stream>>>(users, items, map, logits, out);
}